// Round 8
// baseline (223.817 us; speedup 1.0000x reference)
//
#include <hip/hip_runtime.h>

// SplatAwareFeedForward on MI355X (gfx950).
// Pipeline: prep (weight transposes) -> route (64-row tile list) ->
//           fused expert kernel (prefetch-pipelined: gather+cast x -> GEMM1 -> h in LDS
//           -> GEMM2 -> scatter) -> dense GEMM3 (2-phase) -> dense GEMM4 (8-phase).
// Workspace layout (bytes):
//   g     @ 0        : 33,554,432  (B*S*D bf16; GEMM3 out / GEMM4 in)
//   w1t   @ 33554432 :  8,388,608  (E*[H][D] bf16, transposed W1)
//   w2t   @ 41943040 :  8,388,608  (E*[D][H] bf16, transposed W2)
//   wg1t  @ 50331648 :  2,097,152  ([D][D] bf16, transposed Wg1)
//   wg2t  @ 52428800 :  2,097,152  ([D][D] bf16, transposed Wg2)
//   rout  @ 62914560 : 33,554,432  (B*S*D bf16, routed output, natural order)
//   offs  @ 96468992 : 68          (E+1 ints)
//   order @ 96469248 : 16,384      (S ints sorted by expert)
//   tileE @ 96485632 : 1,280       (expert id per 64-row tile, <=272)
//   tileR @ 96486912 : 1,280       (sorted-row start per tile)
//   ntl   @ 96488192 : 4           (tile count)

#define DEV __device__ __forceinline__

typedef float f32x4 __attribute__((ext_vector_type(4)));
typedef short short8 __attribute__((ext_vector_type(8)));

DEV unsigned short f2bf(float f) {
  unsigned u = __float_as_uint(f);
  u += 0x7fffu + ((u >> 16) & 1u);   // round-to-nearest-even
  return (unsigned short)(u >> 16);
}

DEV void gload16(const void* g, void* l) {
  __builtin_amdgcn_global_load_lds(
      (const __attribute__((address_space(1))) unsigned int*)g,
      (__attribute__((address_space(3))) unsigned int*)l, 16, 0, 0);
}

DEV float gelu_exact(float v) {
  return 0.5f * v * (1.0f + erff(v * 0.70710678118654752f));
}

#define BARRIER() __builtin_amdgcn_s_barrier()
#define VMW(n)    asm volatile("s_waitcnt vmcnt(" #n ")" ::: "memory")

// ---------------- prep: weight transpose-casts only ----------------
__global__ __launch_bounds__(256) void prep_kernel(
    const float* __restrict__ W1, unsigned short* __restrict__ w1t,
    const float* __restrict__ W2, unsigned short* __restrict__ w2t,
    const float* __restrict__ Wg1, unsigned short* __restrict__ wg1t,
    const float* __restrict__ Wg2, unsigned short* __restrict__ wg2t) {
  __shared__ float tile[64][65];
  const int t = threadIdx.x;
  int id = (int)blockIdx.x;
  const float* in; unsigned short* out;
  int R, C, r0, c0; long base;
  if (id < 1024) {
    in = W1; out = w1t; R = 1024; C = 256;
    base = (long)(id >> 6) * 262144;
    r0 = ((id >> 2) & 15) * 64; c0 = (id & 3) * 64;
  } else if (id < 2048) {
    id -= 1024;
    in = W2; out = w2t; R = 256; C = 1024;
    base = (long)(id >> 6) * 262144;
    r0 = ((id >> 4) & 3) * 64; c0 = (id & 15) * 64;
  } else if (id < 2304) {
    id -= 2048;
    in = Wg1; out = wg1t; R = 1024; C = 1024; base = 0;
    r0 = (id >> 4) * 64; c0 = (id & 15) * 64;
  } else {
    id -= 2304;
    in = Wg2; out = wg2t; R = 1024; C = 1024; base = 0;
    r0 = (id >> 4) * 64; c0 = (id & 15) * 64;
  }
  const int cc = t & 63, rr = t >> 6;
#pragma unroll
  for (int i = 0; i < 16; i++) {
    int r = rr + i * 4;
    tile[r][cc] = in[base + (long)(r0 + r) * C + (c0 + cc)];
  }
  __syncthreads();
#pragma unroll
  for (int i = 0; i < 16; i++) {
    int c = rr + i * 4;
    out[base + (long)(c0 + c) * R + (r0 + cc)] = f2bf(tile[cc][c]);
  }
}

// ---------------- routing ----------------
__global__ __launch_bounds__(256) void route_kernel(
    const int* __restrict__ sid, int S, int* __restrict__ offs, int* __restrict__ order,
    int* __restrict__ tileE, int* __restrict__ tileR, int* __restrict__ ntl) {
  __shared__ int cnt[16], cur[16];
  const int t = threadIdx.x;
  if (t < 16) cnt[t] = 0;
  __syncthreads();
  for (int s = t; s < S; s += 256) atomicAdd(&cnt[sid[s]], 1);
  __syncthreads();
  if (t == 0) {
    int a = 0;
    for (int e = 0; e < 16; e++) { offs[e] = a; cur[e] = a; a += cnt[e]; }
    offs[16] = a;
    int nt = 0;
    for (int e = 0; e < 16; e++) {
      const int rows = 4 * cnt[e];
      for (int r = 0; r < rows; r += 64) {
        tileE[nt] = e;
        tileR[nt] = 4 * offs[e] + r;
        nt++;
      }
    }
    ntl[0] = nt;
  }
  __syncthreads();
  for (int s = t; s < S; s += 256) {
    int p = atomicAdd(&cur[sid[s]], 1);
    order[p] = s;
  }
}

// ---------------- fused expert kernel (prefetch-pipelined) ----------------
// Per block: 64 sorted token-rows of expert e.
// Phase A: h[64][256] = gelu(gather(x,f32->bf16) @ W1[e] + b1[e]), h kept in LDS.
//   Double-buffered lA (x tile) and lB (W1 K-slab); stage kt+1 BEFORE computing kt,
//   one __syncthreads per K-step (T3-minimum recipe).
// Phase B: rout[scatter rows][1024] = h @ W2[e] + b2[e]; 32 flattened steps
//   (nc=step>>2 chunk, ks=step&3 K-slab), same stage-ahead pattern.
// 512 threads = 8 waves (2M x 4N). LDS: lA 16KB + lB 64KB + hS 32KB = 112KB (1/CU).
__global__ __launch_bounds__(512, 1) void fused_expert(
    const float* __restrict__ x,
    const unsigned short* __restrict__ w1t, const float* __restrict__ b1,
    const unsigned short* __restrict__ w2t, const float* __restrict__ b2,
    unsigned short* __restrict__ rout,
    const int* __restrict__ order, const int* __restrict__ offs,
    const int* __restrict__ tileE, const int* __restrict__ tileR,
    const int* __restrict__ ntl) {
  constexpr int S = 4096, D = 1024, H = 256;
  const int ti = (int)blockIdx.x;
  if (ti >= ntl[0]) return;

  __shared__ __align__(16) unsigned short lA[2][64 * 64];    // 16KB (x tile, swizzled)
  __shared__ __align__(16) unsigned short lB[2][256 * 64];   // 64KB (W1 slab | 2x W2 slab)
  __shared__ __align__(16) unsigned short hS[64 * 256];      // 32KB (hidden, swizzled)

  const int t = (int)threadIdx.x;
  const int lane = t & 63;
  const int w = t >> 6;
  const int wm = w >> 2;   // 0..1
  const int wn = w & 3;    // 0..3

  const int e = tileE[ti];
  const int rowBase = tileR[ti];
  int Me = 4 * offs[e + 1] - rowBase;
  if (Me > 64) Me = 64;

  // --- phase A setup ---
  const int ar = t >> 3;                       // 0..63 (x row in tile)
  const int arr = (ar < Me) ? ar : (Me - 1);
  const int ga = rowBase + arr;
  const float* xsrc = x + ((long)(ga & 3) * S + order[ga >> 2]) * D + (t & 7) * 8;
  const int aOff = ar * 64 + (((((t & 7) * 16)) ^ ((ar & 7) << 4)) >> 1);

  const unsigned short* b1src[4];
#pragma unroll
  for (int i = 0; i < 4; i++) {
    const int row = i * 64 + (t >> 3);
    b1src[i] = w1t + (long)e * H * D + (long)row * D + ((((t & 7) * 16) ^ ((row & 7) << 4)) >> 1);
  }
  const int dstE = (t >> 3) * 64 + (t & 7) * 8;

  float4 xv0 = *(const float4*)(xsrc);
  float4 xv1 = *(const float4*)(xsrc + 4);

  auto WLA = [&](int b) {                      // cast current xv regs -> lA[b]
    short8 av;
    av[0] = (short)f2bf(xv0.x); av[1] = (short)f2bf(xv0.y);
    av[2] = (short)f2bf(xv0.z); av[3] = (short)f2bf(xv0.w);
    av[4] = (short)f2bf(xv1.x); av[5] = (short)f2bf(xv1.y);
    av[6] = (short)f2bf(xv1.z); av[7] = (short)f2bf(xv1.w);
    *(short8*)(&lA[b][0] + aOff) = av;
  };
  auto STAGE_B1 = [&](int b, int kt) {
#pragma unroll
    for (int i = 0; i < 4; i++) gload16(b1src[i] + (kt << 6), &lB[b][0] + i * 4096 + dstE);
  };

  f32x4 acc[2][4] = {};

  // prologue: buffer 0 <- kt=0; load xv for kt=1
  WLA(0);
  STAGE_B1(0, 0);
  xv0 = *(const float4*)(xsrc + 64);
  xv1 = *(const float4*)(xsrc + 64 + 4);
  __syncthreads();

  for (int kt = 0; kt < 16; kt++) {
    const int cur = kt & 1, nxt = cur ^ 1;
    if (kt < 15) {
      WLA(nxt);                                // xv holds kt+1 data
      STAGE_B1(nxt, kt + 1);
      if (kt < 14) {
        xv0 = *(const float4*)(xsrc + (kt + 2) * 64);
        xv1 = *(const float4*)(xsrc + (kt + 2) * 64 + 4);
      }
    }
#pragma unroll
    for (int kk = 0; kk < 2; kk++) {
      short8 aF[2], bF[4];
      const int kb = kk * 64 + ((lane >> 4) << 4);
#pragma unroll
      for (int mi = 0; mi < 2; mi++) {
        const int row = wm * 32 + mi * 16 + (lane & 15);
        aF[mi] = *(const short8*)((const char*)&lA[cur][0] + row * 128 + (kb ^ ((row & 7) << 4)));
      }
#pragma unroll
      for (int ni = 0; ni < 4; ni++) {
        const int row = wn * 64 + ni * 16 + (lane & 15);
        bF[ni] = *(const short8*)((const char*)&lB[cur][0] + row * 128 + (kb ^ ((row & 7) << 4)));
      }
#pragma unroll
      for (int mi = 0; mi < 2; mi++)
#pragma unroll
        for (int ni = 0; ni < 4; ni++)
          acc[mi][ni] = __builtin_amdgcn_mfma_f32_16x16x32_bf16(aF[mi], bF[ni], acc[mi][ni], 0, 0, 0);
    }
    __syncthreads();                           // nxt staged (vm+lgkm drained), cur free
  }

  // bias + gelu -> hS (swizzled: byte ^= (row&7)<<4 within 512B row)
  {
    float bc[4];
#pragma unroll
    for (int ni = 0; ni < 4; ni++)
      bc[ni] = b1[e * H + wn * 64 + ni * 16 + (lane & 15)];
#pragma unroll
    for (int mi = 0; mi < 2; mi++)
#pragma unroll
      for (int j = 0; j < 4; j++) {
        const int crow = wm * 32 + mi * 16 + ((lane >> 4) << 2) + j;
#pragma unroll
        for (int ni = 0; ni < 4; ni++) {
          const int ccol = wn * 64 + ni * 16 + (lane & 15);
          const float v = gelu_exact(acc[mi][ni][j] + bc[ni]);
          hS[crow * 256 + (((ccol * 2) ^ ((crow & 7) << 4)) >> 1)] = f2bf(v);
        }
      }
  }

  // --- phase B: rout = h @ W2[e] + b2[e]; 32 steps, stage-ahead ---
  // W2 slab for step s (nc=s>>2, ks=s&3): rows nc*128..+128, cols ks*64..+64 (16KB).
  // Buffers: lB[0] and lB[1] each hold one slab in their first 8192 elems.
  const unsigned short* b2base = w2t + (long)e * D * H;   // [1024][256]
  auto STAGE_W2 = [&](int b, int s) {
    const int nc = s >> 2, ks = s & 3;
#pragma unroll
    for (int i = 0; i < 2; i++) {
      const int row = i * 64 + (t >> 3);
      const unsigned short* src = b2base + (long)(nc * 128 + row) * H + (ks << 6) +
                                  ((((t & 7) * 16) ^ ((row & 7) << 4)) >> 1);
      gload16(src, &lB[b][0] + i * 4096 + dstE);
    }
  };

  STAGE_W2(0, 0);
  __syncthreads();                             // hS visible + slab 0 resident

  f32x4 a2[2][2];
  for (int s = 0; s < 32; s++) {
    const int cur = s & 1, nxt = cur ^ 1;
    const int nc = s >> 2, ks = s & 3;
    if (s < 31) STAGE_W2(nxt, s + 1);
    if (ks == 0) {
#pragma unroll
      for (int mi = 0; mi < 2; mi++)
#pragma unroll
        for (int ni = 0; ni < 2; ni++) a2[mi][ni] = (f32x4){0.f, 0.f, 0.f, 0.f};
    }
#pragma unroll
    for (int kk = 0; kk < 2; kk++) {
      short8 aF[2], bF[2];
      const int kbh = ks * 128 + kk * 64 + ((lane >> 4) << 4);   // byte in 512B h-row
      const int kb = kk * 64 + ((lane >> 4) << 4);
#pragma unroll
      for (int mi = 0; mi < 2; mi++) {
        const int row = wm * 32 + mi * 16 + (lane & 15);
        aF[mi] = *(const short8*)((const char*)hS + row * 512 + (kbh ^ ((row & 7) << 4)));
      }
#pragma unroll
      for (int ni = 0; ni < 2; ni++) {
        const int row = wn * 32 + ni * 16 + (lane & 15);
        bF[ni] = *(const short8*)((const char*)&lB[cur][0] + row * 128 + (kb ^ ((row & 7) << 4)));
      }
#pragma unroll
      for (int mi = 0; mi < 2; mi++)
#pragma unroll
        for (int ni = 0; ni < 2; ni++)
          a2[mi][ni] = __builtin_amdgcn_mfma_f32_16x16x32_bf16(aF[mi], bF[ni], a2[mi][ni], 0, 0, 0);
    }
    if (ks == 3) {                             // chunk epilogue: bias + scatter
      float bc2[2];
#pragma unroll
      for (int ni = 0; ni < 2; ni++)
        bc2[ni] = b2[e * D + nc * 128 + wn * 32 + ni * 16 + (lane & 15)];
#pragma unroll
      for (int mi = 0; mi < 2; mi++)
#pragma unroll
        for (int j = 0; j < 4; j++) {
          const int lrow = wm * 32 + mi * 16 + ((lane >> 4) << 2) + j;
          if (lrow >= Me) continue;
          const int g = rowBase + lrow;
          const long crow = (long)(g & 3) * S + order[g >> 2];
#pragma unroll
          for (int ni = 0; ni < 2; ni++) {
            const float v = a2[mi][ni][j] + bc2[ni];
            rout[crow * D + nc * 128 + wn * 32 + ni * 16 + (lane & 15)] = f2bf(v);
          }
        }
    }
    __syncthreads();                           // next slab resident, cur free
  }
}

// ---------------- dense 256x256x64 GEMM, 2-phase T3-minimum recipe ----------------
template <bool GELU, bool OUT_F32>
__global__ __launch_bounds__(512, 1) void gemm_2ph(
    const unsigned short* __restrict__ A, const unsigned short* __restrict__ BT,
    const float* __restrict__ bias, void* __restrict__ Cout,
    int N, int K, int ntiles) {
  __shared__ __align__(16) unsigned short lds[2][2][256 * 64];  // [buf][A/B] 128KB

  const int t = (int)threadIdx.x;
  const int lane = t & 63;
  const int w = t >> 6;
  const int wm = w >> 2;   // 0..1
  const int wn = w & 3;    // 0..3

  const int cpx = (int)gridDim.x >> 3;
  const int swz = ((int)blockIdx.x & 7) * cpx + ((int)blockIdx.x >> 3);
  const int mtile = swz / ntiles, ntile = swz % ntiles;

  const int tq = t & 7;
  const unsigned short* srcA[4];
  const unsigned short* srcB[4];
#pragma unroll
  for (int i = 0; i < 4; i++) {
    const int row = i * 64 + (t >> 3);
    const int koffE = ((tq * 16) ^ ((row & 7) << 4)) >> 1;
    srcA[i] = A + (long)(mtile * 256 + row) * K + koffE;
    srcB[i] = BT + (long)(ntile * 256 + row) * K + koffE;
  }
  const int dstE = (t >> 3) * 64 + tq * 8;

  auto STAGE = [&](int buf, int kt) {
    const long ko = (long)kt << 6;
#pragma unroll
    for (int i = 0; i < 4; i++) gload16(srcA[i] + ko, &lds[buf][0][i * 4096 + dstE]);
#pragma unroll
    for (int i = 0; i < 4; i++) gload16(srcB[i] + ko, &lds[buf][1][i * 4096 + dstE]);
  };

  f32x4 acc[8][4] = {};
  const int KT = K >> 6;

  STAGE(0, 0);
  __syncthreads();

  int buf = 0;
  for (int kt = 0; kt < KT; kt++) {
    if (kt + 1 < KT) STAGE(buf ^ 1, kt + 1);
#pragma unroll
    for (int kk = 0; kk < 2; kk++) {
      short8 aF[8], bF[4];
      const int kb = kk * 64 + ((lane >> 4) << 4);
#pragma unroll
      for (int m = 0; m < 8; m++) {
        const int row = wm * 128 + m * 16 + (lane & 15);
        aF[m] = *(const short8*)((const char*)&lds[buf][0][0] + row * 128 + (kb ^ ((row & 7) << 4)));
      }
#pragma unroll
      for (int n = 0; n < 4; n++) {
        const int row = wn * 64 + n * 16 + (lane & 15);
        bF[n] = *(const short8*)((const char*)&lds[buf][1][0] + row * 128 + (kb ^ ((row & 7) << 4)));
      }
      __builtin_amdgcn_s_setprio(1);
#pragma unroll
      for (int m = 0; m < 8; m++)
#pragma unroll
        for (int n = 0; n < 4; n++)
          acc[m][n] = __builtin_amdgcn_mfma_f32_16x16x32_bf16(aF[m], bF[n], acc[m][n], 0, 0, 0);
      __builtin_amdgcn_s_setprio(0);
    }
    __syncthreads();
    buf ^= 1;
  }

  float bcol[4];
#pragma unroll
  for (int n = 0; n < 4; n++)
    bcol[n] = bias[ntile * 256 + wn * 64 + n * 16 + (lane & 15)];
  const int cbase = ntile * 256 + wn * 64 + (lane & 15);
#pragma unroll
  for (int m = 0; m < 8; m++) {
#pragma unroll
    for (int j = 0; j < 4; j++) {
      const long crow = mtile * 256 + wm * 128 + m * 16 + ((lane >> 4) << 2) + j;
#pragma unroll
      for (int n = 0; n < 4; n++) {
        float v = acc[m][n][j] + bcol[n];
        if (GELU) v = gelu_exact(v);
        const long cidx = crow * (long)N + cbase + n * 16;
        if (OUT_F32) ((float*)Cout)[cidx] = v;
        else ((unsigned short*)Cout)[cidx] = f2bf(v);
      }
    }
  }
}

// ---------------- dense 256x256x64 GEMM, 8-phase (control, unchanged) ----------------
template <bool GELU, bool OUT_F32>
__global__ __launch_bounds__(512, 2) void gemm_8phase(
    const unsigned short* __restrict__ A, const unsigned short* __restrict__ BT,
    const float* __restrict__ bias, void* __restrict__ Cout,
    int N, int K, int ntiles) {
  __shared__ __align__(16) unsigned short lds[8 * 8192];

  const int t = (int)threadIdx.x;
  const int lane = t & 63;
  const int w = t >> 6;
  const int wm = w >> 2;
  const int wn = w & 3;

  const int cpx = (int)gridDim.x >> 3;
  const int swz = ((int)blockIdx.x & 7) * cpx + ((int)blockIdx.x >> 3);
  const int mtile = swz / ntiles, ntile = swz % ntiles;

  const int tq = t & 7;
  const unsigned short* srcA[2][2];
  const unsigned short* srcB[2][2];
#pragma unroll
  for (int i = 0; i < 2; i++) {
    const int ir = i * 64 + (t >> 3);
    const int koffE = ((tq * 16) ^ ((ir & 7) << 4)) >> 1;
#pragma unroll
    for (int h = 0; h < 2; h++) {
      const int ra = (ir & 63) + (h << 6) + ((ir >> 6) << 7);
      srcA[i][h] = A + (long)(mtile * 256 + ra) * K + koffE;
      const int cb = (ir & 31) + (h << 5) + ((ir >> 5) << 6);
      srcB[i][h] = BT + (long)(ntile * 256 + cb) * K + koffE;
    }
  }
  const int dstE = (t >> 3) * 64 + tq * 8;

  auto STAGE = [&](int d, int mat, int h, int kt) {
    unsigned short* dst = lds + ((d * 4 + mat * 2 + h) << 13) + dstE;
    const unsigned short* s0 = (mat == 0 ? srcA[0][h] : srcB[0][h]) + (kt << 6);
    const unsigned short* s1 = (mat == 0 ? srcA[1][h] : srcB[1][h]) + (kt << 6);
    gload16(s0, dst);
    gload16(s1, dst + 4096);
  };

  short8 aReg[8], bReg[8];
  const int klane = (lane >> 4) << 4;
  const int rsw = (lane & 7) << 4;

  auto LDA = [&](int d, int mh) {
    const char* base = (const char*)(lds + ((d * 4 + mh) << 13));
    const int r0 = wm * 64 + (lane & 15);
#pragma unroll
    for (int m = 0; m < 4; m++) {
      const int row = r0 + m * 16;
#pragma unroll
      for (int kk = 0; kk < 2; kk++)
        aReg[m * 2 + kk] = *(const short8*)(base + row * 128 + ((kk * 64 + klane) ^ rsw));
    }
  };
  auto LDB = [&](int d, int nh) {
    const char* base = (const char*)(lds + ((d * 4 + 2 + nh) << 13));
    const int r0 = wn * 32 + (lane & 15);
#pragma unroll
    for (int n = 0; n < 2; n++) {
      const int row = r0 + n * 16;
#pragma unroll
      for (int kk = 0; kk < 2; kk++)
        bReg[(nh * 2 + n) * 2 + kk] = *(const short8*)(base + row * 128 + ((kk * 64 + klane) ^ rsw));
    }
  };

  f32x4 acc[8][4] = {};
  auto MMA = [&](int mb, int nb) {
    __builtin_amdgcn_s_setprio(1);
#pragma unroll
    for (int kk = 0; kk < 2; kk++)
#pragma unroll
      for (int m = 0; m < 4; m++)
#pragma unroll
        for (int n = 0; n < 2; n++)
          acc[mb + m][nb + n] = __builtin_amdgcn_mfma_f32_16x16x32_bf16(
              aReg[m * 2 + kk], bReg[(nb + n) * 2 + kk], acc[mb + m][nb + n], 0, 0, 0);
    __builtin_amdgcn_s_setprio(0);
  };

  const int KT = K >> 6;

  {
    const int t1 = (KT > 1) ? 1 : 0;
    STAGE(0, 0, 0, 0); STAGE(0, 1, 0, 0); STAGE(0, 1, 1, 0); STAGE(0, 0, 1, 0);
    STAGE(1, 0, 0, t1); STAGE(1, 1, 0, t1); STAGE(1, 1, 1, t1);
    VMW(6);
    BARRIER();
  }

  for (int it = 0; it < (KT >> 1); ++it) {
    const int tb = (2 * it + 1 < KT) ? 2 * it + 1 : KT - 1;
    int nx = 2 * it + 2; if (nx >= KT) nx = KT - 1;
    int ny = 2 * it + 3; if (ny >= KT) ny = KT - 1;
    LDA(0, 0); LDB(0, 0); STAGE(1, 0, 1, tb);
    BARRIER();
    MMA(0, 0);
    BARRIER();
    LDB(0, 1); STAGE(0, 0, 0, nx);
    BARRIER();
    MMA(0, 2);
    BARRIER();
    LDA(0, 1); STAGE(0, 1, 0, nx);
    BARRIER();
    MMA(4, 0);
    BARRIER();
    STAGE(0, 1, 1, nx);
    BARRIER();
    MMA(4, 2);
    VMW(6);
    BARRIER();
    LDA(1, 0); LDB(1, 0); STAGE(0, 0, 1, nx);
    BARRIER();
    MMA(0, 0);
    BARRIER();
    LDB(1, 1); STAGE(1, 0, 0, ny);
    BARRIER();
    MMA(0, 2);
    BARRIER();
    LDA(1, 1); STAGE(1, 1, 0, ny);
    BARRIER();
    MMA(4, 0);
    BARRIER();
    STAGE(1, 1, 1, ny);
    BARRIER();
    MMA(4, 2);
    VMW(6);
    BARRIER();
  }
  VMW(0);

  float bcol[4];
#pragma unroll
  for (int n = 0; n < 4; n++)
    bcol[n] = bias[ntile * 256 + wn * 64 + n * 16 + (lane & 15)];
  const int cbase = ntile * 256 + wn * 64 + (lane & 15);
#pragma unroll
  for (int m = 0; m < 8; m++) {
#pragma unroll
    for (int j = 0; j < 4; j++) {
      const long crow = mtile * 256 + wm * 128 + m * 16 + ((lane >> 4) << 2) + j;
#pragma unroll
      for (int n = 0; n < 4; n++) {
        float v = acc[m][n][j] + bcol[n];
        if (GELU) v = gelu_exact(v);
        const long cidx = crow * (long)N + cbase + n * 16;
        if (OUT_F32) ((float*)Cout)[cidx] = v;
        else ((unsigned short*)Cout)[cidx] = f2bf(v);
      }
    }
  }
}

extern "C" void kernel_launch(void* const* d_in, const int* in_sizes, int n_in,
                              void* d_out, int out_size, void* d_ws, size_t ws_size,
                              hipStream_t stream) {
  const float* x   = (const float*)d_in[0];
  const int*   sid = (const int*)d_in[1];
  const float* W1  = (const float*)d_in[2];
  const float* b1  = (const float*)d_in[3];
  const float* W2  = (const float*)d_in[4];
  const float* b2  = (const float*)d_in[5];
  const float* Wg1 = (const float*)d_in[6];
  const float* bg1 = (const float*)d_in[7];
  const float* Wg2 = (const float*)d_in[8];
  const float* bg2 = (const float*)d_in[9];
  (void)in_sizes; (void)n_in; (void)out_size; (void)ws_size;

  constexpr int D = 1024, S = 4096, B = 4;
  constexpr long NT = (long)B * S;

  char* ws = (char*)d_ws;
  unsigned short* g    = (unsigned short*)(ws);
  unsigned short* w1t  = (unsigned short*)(ws + 33554432);
  unsigned short* w2t  = (unsigned short*)(ws + 41943040);
  unsigned short* wg1t = (unsigned short*)(ws + 50331648);
  unsigned short* wg2t = (unsigned short*)(ws + 52428800);
  unsigned short* rout = (unsigned short*)(ws + 62914560);
  int* offs  = (int*)(ws + 96468992);
  int* order = (int*)(ws + 96469248);
  int* tileE = (int*)(ws + 96485632);
  int* tileR = (int*)(ws + 96486912);
  int* ntl   = (int*)(ws + 96488192);

  prep_kernel<<<dim3(2560), 256, 0, stream>>>(W1, w1t, W2, w2t, Wg1, wg1t, Wg2, wg2t);
  route_kernel<<<1, 256, 0, stream>>>(sid, S, offs, order, tileE, tileR, ntl);

  // fused experts: gather+cast x -> GEMM1 -> h(LDS) -> GEMM2 -> scatter to rout
  fused_expert<<<dim3(272), 512, 0, stream>>>(
      x, w1t, b1, w2t, b2, rout, order, offs, tileE, tileR, ntl);

  // GEMM3: g = gelu(rout @ Wg1 + bg1)   [2-phase arm]
  gemm_2ph<true, false><<<dim3((unsigned)(NT / 256) * (D / 256)), 512, 0, stream>>>(
      rout, wg1t, bg1, g, D, D, D / 256);
  // GEMM4: out = g @ Wg2 + bg2          [8-phase arm]
  gemm_8phase<false, true><<<dim3((unsigned)(NT / 256) * (D / 256)), 512, 0, stream>>>(
      g, wg2t, bg2, d_out, D, D, D / 256);
}

// Round 9
// 186.535 us; speedup vs baseline: 1.1999x; 1.1999x over previous
//
#include <hip/hip_runtime.h>

// SplatAwareFeedForward on MI355X (gfx950).
// Pipeline: prep (x-cast + weight transposes) -> route (tile lists) ->
//           expert GEMM1/GEMM2 (m97-style, compact grids) ->
//           dense GEMM3 (2-phase) -> dense GEMM4 (8-phase).   [dense A/B readout]
// Workspace layout (bytes):
//   xb    @ 0        : 33,554,432  (B*S*D bf16; reused as g-buffer for GEMM4 input)
//   w1t   @ 33554432 :  8,388,608  (E*[H][D] bf16, transposed W1)
//   w2t   @ 41943040 :  8,388,608  (E*[D][H] bf16, transposed W2)
//   wg1t  @ 50331648 :  2,097,152  ([D][D] bf16, transposed Wg1)
//   wg2t  @ 52428800 :  2,097,152  ([D][D] bf16, transposed Wg2)
//   hbuf  @ 54525952 :  8,388,608  (B*S*H bf16, expert-sorted hidden)
//   rout  @ 62914560 : 33,554,432  (B*S*D bf16, routed output, natural order)
//   offs  @ 96468992 : 68          (E+1 ints)
//   order @ 96469248 : 16,384      (S ints sorted by expert)
//   tileE @ 96485632 : 576         (expert id per 128-row tile, <=144)
//   tileR @ 96486208 : 576         (sorted-row start per tile)
//   ntl   @ 96486784 : 4           (tile count)

#define DEV __device__ __forceinline__

typedef float f32x4 __attribute__((ext_vector_type(4)));
typedef short short8 __attribute__((ext_vector_type(8)));

DEV unsigned short f2bf(float f) {
  unsigned u = __float_as_uint(f);
  u += 0x7fffu + ((u >> 16) & 1u);   // round-to-nearest-even
  return (unsigned short)(u >> 16);
}

DEV void gload16(const void* g, void* l) {
  __builtin_amdgcn_global_load_lds(
      (const __attribute__((address_space(1))) unsigned int*)g,
      (__attribute__((address_space(3))) unsigned int*)l, 16, 0, 0);
}

DEV float gelu_exact(float v) {
  return 0.5f * v * (1.0f + erff(v * 0.70710678118654752f));
}

#define BARRIER() __builtin_amdgcn_s_barrier()
#define VMW(n)    asm volatile("s_waitcnt vmcnt(" #n ")" ::: "memory")

// ---------------- prep: x-cast + all transpose-casts in ONE launch ----------------
// blocks [0,8192): cast x (16M f32 -> bf16, 2048 elems/block)
// blocks [8192,9216): W1 tiles; [9216,10240): W2; [10240,10496): Wg1; [10496,10752): Wg2
__global__ __launch_bounds__(256) void prep_kernel(
    const float* __restrict__ x, unsigned short* __restrict__ xb,
    const float* __restrict__ W1, unsigned short* __restrict__ w1t,
    const float* __restrict__ W2, unsigned short* __restrict__ w2t,
    const float* __restrict__ Wg1, unsigned short* __restrict__ wg1t,
    const float* __restrict__ Wg2, unsigned short* __restrict__ wg2t) {
  __shared__ float tile[64][65];
  const int t = threadIdx.x;
  int id = (int)blockIdx.x;
  if (id < 8192) {
    long i = ((long)id * 256 + t) * 8;
    float4 v0 = *(const float4*)(x + i);
    float4 v1 = *(const float4*)(x + i + 4);
    uint4 o;
    o.x = (unsigned)f2bf(v0.x) | ((unsigned)f2bf(v0.y) << 16);
    o.y = (unsigned)f2bf(v0.z) | ((unsigned)f2bf(v0.w) << 16);
    o.z = (unsigned)f2bf(v1.x) | ((unsigned)f2bf(v1.y) << 16);
    o.w = (unsigned)f2bf(v1.z) | ((unsigned)f2bf(v1.w) << 16);
    *(uint4*)(xb + i) = o;
    return;
  }
  id -= 8192;
  const float* in; unsigned short* out;
  int R, C, r0, c0; long base;
  if (id < 1024) {          // W1: [1024][256] -> [256][1024] per expert
    in = W1; out = w1t; R = 1024; C = 256;
    base = (long)(id >> 6) * 262144;
    r0 = ((id >> 2) & 15) * 64; c0 = (id & 3) * 64;
  } else if (id < 2048) {   // W2: [256][1024] -> [1024][256] per expert
    id -= 1024;
    in = W2; out = w2t; R = 256; C = 1024;
    base = (long)(id >> 6) * 262144;
    r0 = ((id >> 4) & 3) * 64; c0 = (id & 15) * 64;
  } else if (id < 2304) {   // Wg1
    id -= 2048;
    in = Wg1; out = wg1t; R = 1024; C = 1024; base = 0;
    r0 = (id >> 4) * 64; c0 = (id & 15) * 64;
  } else {                  // Wg2
    id -= 2304;
    in = Wg2; out = wg2t; R = 1024; C = 1024; base = 0;
    r0 = (id >> 4) * 64; c0 = (id & 15) * 64;
  }
  const int cc = t & 63, rr = t >> 6;
#pragma unroll
  for (int i = 0; i < 16; i++) {
    int r = rr + i * 4;
    tile[r][cc] = in[base + (long)(r0 + r) * C + (c0 + cc)];
  }
  __syncthreads();
#pragma unroll
  for (int i = 0; i < 16; i++) {
    int c = rr + i * 4;
    out[base + (long)(c0 + c) * R + (r0 + cc)] = f2bf(tile[cc][c]);
  }
}

// ---------------- routing: counts -> prefix -> sorted order -> 128-row tile list ----------------
__global__ __launch_bounds__(256) void route_kernel(
    const int* __restrict__ sid, int S, int* __restrict__ offs, int* __restrict__ order,
    int* __restrict__ tileE, int* __restrict__ tileR, int* __restrict__ ntl) {
  __shared__ int cnt[16], cur[16];
  const int t = threadIdx.x;
  if (t < 16) cnt[t] = 0;
  __syncthreads();
  for (int s = t; s < S; s += 256) atomicAdd(&cnt[sid[s]], 1);
  __syncthreads();
  if (t == 0) {
    int a = 0;
    for (int e = 0; e < 16; e++) { offs[e] = a; cur[e] = a; a += cnt[e]; }
    offs[16] = a;
    int nt = 0;
    for (int e = 0; e < 16; e++) {
      const int rows = 4 * cnt[e];
      for (int r = 0; r < rows; r += 128) {
        tileE[nt] = e;
        tileR[nt] = 4 * offs[e] + r;
        nt++;
      }
    }
    ntl[0] = nt;
  }
  __syncthreads();
  for (int s = t; s < S; s += 256) {
    int p = atomicAdd(&cur[sid[s]], 1);
    order[p] = s;
  }
}

// ---------------- expert 128x128x64 bf16 MFMA GEMM (m97-style, compact tile grid) ----------------
template <bool GATHER_A, bool SCATTER_C, bool GELU, bool OUT_F32>
__global__ __launch_bounds__(256) void gemm_mfma(
    const unsigned short* __restrict__ A, const unsigned short* __restrict__ BT,
    const float* __restrict__ bias, void* __restrict__ Cout,
    int N, int K,
    const int* __restrict__ order, const int* __restrict__ offs,
    const int* __restrict__ tileE, const int* __restrict__ tileR,
    const int* __restrict__ ntl,
    int S, long btStride, int biasStride) {
  const int ti = (int)blockIdx.y;
  if (ti >= ntl[0]) return;
  const int t = (int)threadIdx.x;
  const int lane = t & 63;
  const int w = t >> 6;
  const int wm = w >> 1, wn = w & 1;
  const int tileN = (int)blockIdx.x;

  const int e = tileE[ti];
  const int rowBase = tileR[ti];
  int Me = 4 * offs[e + 1] - rowBase;
  if (Me > 128) Me = 128;
  const unsigned short* bt = BT + (long)e * btStride;
  const float* bs = bias + (long)e * biasStride;

  __shared__ __align__(16) unsigned short lA[128 * 64];
  __shared__ __align__(16) unsigned short lB[128 * 64];

  const unsigned short* aSrc[4];
  const unsigned short* bSrc[4];
  {
    const int q = t & 7;
#pragma unroll
    for (int i = 0; i < 4; i++) {
      const int row = i * 32 + (t >> 3);
      const int koff = ((q * 16) ^ ((row & 7) << 4)) >> 1;
      const int rr = (row < Me) ? row : (Me - 1);
      const int g = rowBase + rr;
      long arow;
      if (GATHER_A) {
        const int s = order[g >> 2];
        arow = (long)(g & 3) * S + s;
      } else {
        arow = g;
      }
      aSrc[i] = A + arow * (long)K + koff;
      const int col = tileN * 128 + row;
      bSrc[i] = bt + (long)col * K + koff;
    }
  }

  f32x4 acc[4][4] = {};

  const int KT = K >> 6;
  for (int kt = 0; kt < KT; kt++) {
    __syncthreads();
#pragma unroll
    for (int i = 0; i < 4; i++) {
      gload16(aSrc[i] + (kt << 6), (void*)(lA + i * 2048 + w * 512));
      gload16(bSrc[i] + (kt << 6), (void*)(lB + i * 2048 + w * 512));
    }
    __syncthreads();
#pragma unroll
    for (int kk = 0; kk < 2; kk++) {
      short8 af[4], bfr[4];
      const int kbyte = kk * 64 + (lane >> 4) * 16;
#pragma unroll
      for (int mi = 0; mi < 4; mi++) {
        const int row = wm * 64 + mi * 16 + (lane & 15);
        const int off = row * 128 + (kbyte ^ ((row & 7) << 4));
        af[mi] = *(const short8*)((const char*)lA + off);
      }
#pragma unroll
      for (int ni = 0; ni < 4; ni++) {
        const int row = wn * 64 + ni * 16 + (lane & 15);
        const int off = row * 128 + (kbyte ^ ((row & 7) << 4));
        bfr[ni] = *(const short8*)((const char*)lB + off);
      }
#pragma unroll
      for (int mi = 0; mi < 4; mi++)
#pragma unroll
        for (int ni = 0; ni < 4; ni++)
          acc[mi][ni] = __builtin_amdgcn_mfma_f32_16x16x32_bf16(af[mi], bfr[ni], acc[mi][ni], 0, 0, 0);
    }
  }

  float bcol[4];
#pragma unroll
  for (int ni = 0; ni < 4; ni++)
    bcol[ni] = bs[tileN * 128 + wn * 64 + ni * 16 + (lane & 15)];

#pragma unroll
  for (int mi = 0; mi < 4; mi++) {
#pragma unroll
    for (int j = 0; j < 4; j++) {
      const int lrow = wm * 64 + mi * 16 + ((lane >> 4) * 4) + j;
      if (lrow >= Me) continue;
      const int g = rowBase + lrow;
      long crow;
      if (SCATTER_C) crow = (long)(g & 3) * S + order[g >> 2];
      else crow = g;
#pragma unroll
      for (int ni = 0; ni < 4; ni++) {
        float v = acc[mi][ni][j] + bcol[ni];
        if (GELU) v = gelu_exact(v);
        const long cidx = crow * (long)N + tileN * 128 + wn * 64 + ni * 16 + (lane & 15);
        if (OUT_F32) ((float*)Cout)[cidx] = v;
        else ((unsigned short*)Cout)[cidx] = f2bf(v);
      }
    }
  }
}

// ---------------- dense 256x256x64 GEMM, 2-phase T3-minimum recipe ----------------
template <bool GELU, bool OUT_F32>
__global__ __launch_bounds__(512, 1) void gemm_2ph(
    const unsigned short* __restrict__ A, const unsigned short* __restrict__ BT,
    const float* __restrict__ bias, void* __restrict__ Cout,
    int N, int K, int ntiles) {
  __shared__ __align__(16) unsigned short lds[2][2][256 * 64];  // 128KB

  const int t = (int)threadIdx.x;
  const int lane = t & 63;
  const int w = t >> 6;
  const int wm = w >> 2;   // 0..1
  const int wn = w & 3;    // 0..3

  const int cpx = (int)gridDim.x >> 3;
  const int swz = ((int)blockIdx.x & 7) * cpx + ((int)blockIdx.x >> 3);
  const int mtile = swz / ntiles, ntile = swz % ntiles;

  const int tq = t & 7;
  const unsigned short* srcA[4];
  const unsigned short* srcB[4];
#pragma unroll
  for (int i = 0; i < 4; i++) {
    const int row = i * 64 + (t >> 3);
    const int koffE = ((tq * 16) ^ ((row & 7) << 4)) >> 1;
    srcA[i] = A + (long)(mtile * 256 + row) * K + koffE;
    srcB[i] = BT + (long)(ntile * 256 + row) * K + koffE;
  }
  const int dstE = (t >> 3) * 64 + tq * 8;

  auto STAGE = [&](int buf, int kt) {
    const long ko = (long)kt << 6;
#pragma unroll
    for (int i = 0; i < 4; i++) gload16(srcA[i] + ko, &lds[buf][0][i * 4096 + dstE]);
#pragma unroll
    for (int i = 0; i < 4; i++) gload16(srcB[i] + ko, &lds[buf][1][i * 4096 + dstE]);
  };

  f32x4 acc[8][4] = {};
  const int KT = K >> 6;

  STAGE(0, 0);
  __syncthreads();

  int buf = 0;
  for (int kt = 0; kt < KT; kt++) {
    if (kt + 1 < KT) STAGE(buf ^ 1, kt + 1);
#pragma unroll
    for (int kk = 0; kk < 2; kk++) {
      short8 aF[8], bF[4];
      const int kb = kk * 64 + ((lane >> 4) << 4);
#pragma unroll
      for (int m = 0; m < 8; m++) {
        const int row = wm * 128 + m * 16 + (lane & 15);
        aF[m] = *(const short8*)((const char*)&lds[buf][0][0] + row * 128 + (kb ^ ((row & 7) << 4)));
      }
#pragma unroll
      for (int n = 0; n < 4; n++) {
        const int row = wn * 64 + n * 16 + (lane & 15);
        bF[n] = *(const short8*)((const char*)&lds[buf][1][0] + row * 128 + (kb ^ ((row & 7) << 4)));
      }
      __builtin_amdgcn_s_setprio(1);
#pragma unroll
      for (int m = 0; m < 8; m++)
#pragma unroll
        for (int n = 0; n < 4; n++)
          acc[m][n] = __builtin_amdgcn_mfma_f32_16x16x32_bf16(aF[m], bF[n], acc[m][n], 0, 0, 0);
      __builtin_amdgcn_s_setprio(0);
    }
    __syncthreads();
    buf ^= 1;
  }

  float bcol[4];
#pragma unroll
  for (int n = 0; n < 4; n++)
    bcol[n] = bias[ntile * 256 + wn * 64 + n * 16 + (lane & 15)];
  const int cbase = ntile * 256 + wn * 64 + (lane & 15);
#pragma unroll
  for (int m = 0; m < 8; m++) {
#pragma unroll
    for (int j = 0; j < 4; j++) {
      const long crow = mtile * 256 + wm * 128 + m * 16 + ((lane >> 4) << 2) + j;
#pragma unroll
      for (int n = 0; n < 4; n++) {
        float v = acc[m][n][j] + bcol[n];
        if (GELU) v = gelu_exact(v);
        const long cidx = crow * (long)N + cbase + n * 16;
        if (OUT_F32) ((float*)Cout)[cidx] = v;
        else ((unsigned short*)Cout)[cidx] = f2bf(v);
      }
    }
  }
}

// ---------------- dense 256x256x64 GEMM, 8-phase (control, unchanged) ----------------
template <bool GELU, bool OUT_F32>
__global__ __launch_bounds__(512, 2) void gemm_8phase(
    const unsigned short* __restrict__ A, const unsigned short* __restrict__ BT,
    const float* __restrict__ bias, void* __restrict__ Cout,
    int N, int K, int ntiles) {
  __shared__ __align__(16) unsigned short lds[8 * 8192];

  const int t = (int)threadIdx.x;
  const int lane = t & 63;
  const int w = t >> 6;
  const int wm = w >> 2;
  const int wn = w & 3;

  const int cpx = (int)gridDim.x >> 3;
  const int swz = ((int)blockIdx.x & 7) * cpx + ((int)blockIdx.x >> 3);
  const int mtile = swz / ntiles, ntile = swz % ntiles;

  const int tq = t & 7;
  const unsigned short* srcA[2][2];
  const unsigned short* srcB[2][2];
#pragma unroll
  for (int i = 0; i < 2; i++) {
    const int ir = i * 64 + (t >> 3);
    const int koffE = ((tq * 16) ^ ((ir & 7) << 4)) >> 1;
#pragma unroll
    for (int h = 0; h < 2; h++) {
      const int ra = (ir & 63) + (h << 6) + ((ir >> 6) << 7);
      srcA[i][h] = A + (long)(mtile * 256 + ra) * K + koffE;
      const int cb = (ir & 31) + (h << 5) + ((ir >> 5) << 6);
      srcB[i][h] = BT + (long)(ntile * 256 + cb) * K + koffE;
    }
  }
  const int dstE = (t >> 3) * 64 + tq * 8;

  auto STAGE = [&](int d, int mat, int h, int kt) {
    unsigned short* dst = lds + ((d * 4 + mat * 2 + h) << 13) + dstE;
    const unsigned short* s0 = (mat == 0 ? srcA[0][h] : srcB[0][h]) + (kt << 6);
    const unsigned short* s1 = (mat == 0 ? srcA[1][h] : srcB[1][h]) + (kt << 6);
    gload16(s0, dst);
    gload16(s1, dst + 4096);
  };

  short8 aReg[8], bReg[8];
  const int klane = (lane >> 4) << 4;
  const int rsw = (lane & 7) << 4;

  auto LDA = [&](int d, int mh) {
    const char* base = (const char*)(lds + ((d * 4 + mh) << 13));
    const int r0 = wm * 64 + (lane & 15);
#pragma unroll
    for (int m = 0; m < 4; m++) {
      const int row = r0 + m * 16;
#pragma unroll
      for (int kk = 0; kk < 2; kk++)
        aReg[m * 2 + kk] = *(const short8*)(base + row * 128 + ((kk * 64 + klane) ^ rsw));
    }
  };
  auto LDB = [&](int d, int nh) {
    const char* base = (const char*)(lds + ((d * 4 + 2 + nh) << 13));
    const int r0 = wn * 32 + (lane & 15);
#pragma unroll
    for (int n = 0; n < 2; n++) {
      const int row = r0 + n * 16;
#pragma unroll
      for (int kk = 0; kk < 2; kk++)
        bReg[(nh * 2 + n) * 2 + kk] = *(const short8*)(base + row * 128 + ((kk * 64 + klane) ^ rsw));
    }
  };

  f32x4 acc[8][4] = {};
  auto MMA = [&](int mb, int nb) {
    __builtin_amdgcn_s_setprio(1);
#pragma unroll
    for (int kk = 0; kk < 2; kk++)
#pragma unroll
      for (int m = 0; m < 4; m++)
#pragma unroll
        for (int n = 0; n < 2; n++)
          acc[mb + m][nb + n] = __builtin_amdgcn_mfma_f32_16x16x32_bf16(
              aReg[m * 2 + kk], bReg[(nb + n) * 2 + kk], acc[mb + m][nb + n], 0, 0, 0);
    __builtin_amdgcn_s_setprio(0);
  };

  const int KT = K >> 6;

  {
    const int t1 = (KT > 1) ? 1 : 0;
    STAGE(0, 0, 0, 0); STAGE(0, 1, 0, 0); STAGE(0, 1, 1, 0); STAGE(0, 0, 1, 0);
    STAGE(1, 0, 0, t1); STAGE(1, 1, 0, t1); STAGE(1, 1, 1, t1);
    VMW(6);
    BARRIER();
  }

  for (int it = 0; it < (KT >> 1); ++it) {
    const int tb = (2 * it + 1 < KT) ? 2 * it + 1 : KT - 1;
    int nx = 2 * it + 2; if (nx >= KT) nx = KT - 1;
    int ny = 2 * it + 3; if (ny >= KT) ny = KT - 1;
    LDA(0, 0); LDB(0, 0); STAGE(1, 0, 1, tb);
    BARRIER();
    MMA(0, 0);
    BARRIER();
    LDB(0, 1); STAGE(0, 0, 0, nx);
    BARRIER();
    MMA(0, 2);
    BARRIER();
    LDA(0, 1); STAGE(0, 1, 0, nx);
    BARRIER();
    MMA(4, 0);
    BARRIER();
    STAGE(0, 1, 1, nx);
    BARRIER();
    MMA(4, 2);
    VMW(6);
    BARRIER();
    LDA(1, 0); LDB(1, 0); STAGE(0, 0, 1, nx);
    BARRIER();
    MMA(0, 0);
    BARRIER();
    LDB(1, 1); STAGE(1, 0, 0, ny);
    BARRIER();
    MMA(0, 2);
    BARRIER();
    LDA(1, 1); STAGE(1, 1, 0, ny);
    BARRIER();
    MMA(4, 0);
    BARRIER();
    STAGE(1, 1, 1, ny);
    BARRIER();
    MMA(4, 2);
    VMW(6);
    BARRIER();
  }
  VMW(0);

  float bcol[4];
#pragma unroll
  for (int n = 0; n < 4; n++)
    bcol[n] = bias[ntile * 256 + wn * 64 + n * 16 + (lane & 15)];
  const int cbase = ntile * 256 + wn * 64 + (lane & 15);
#pragma unroll
  for (int m = 0; m < 8; m++) {
#pragma unroll
    for (int j = 0; j < 4; j++) {
      const long crow = mtile * 256 + wm * 128 + m * 16 + ((lane >> 4) << 2) + j;
#pragma unroll
      for (int n = 0; n < 4; n++) {
        float v = acc[m][n][j] + bcol[n];
        if (GELU) v = gelu_exact(v);
        const long cidx = crow * (long)N + cbase + n * 16;
        if (OUT_F32) ((float*)Cout)[cidx] = v;
        else ((unsigned short*)Cout)[cidx] = f2bf(v);
      }
    }
  }
}

extern "C" void kernel_launch(void* const* d_in, const int* in_sizes, int n_in,
                              void* d_out, int out_size, void* d_ws, size_t ws_size,
                              hipStream_t stream) {
  const float* x   = (const float*)d_in[0];
  const int*   sid = (const int*)d_in[1];
  const float* W1  = (const float*)d_in[2];
  const float* b1  = (const float*)d_in[3];
  const float* W2  = (const float*)d_in[4];
  const float* b2  = (const float*)d_in[5];
  const float* Wg1 = (const float*)d_in[6];
  const float* bg1 = (const float*)d_in[7];
  const float* Wg2 = (const float*)d_in[8];
  const float* bg2 = (const float*)d_in[9];
  (void)in_sizes; (void)n_in; (void)out_size; (void)ws_size;

  constexpr int D = 1024, H = 256, S = 4096, B = 4;
  constexpr long NT = (long)B * S;  // 16384 token rows

  char* ws = (char*)d_ws;
  unsigned short* xb   = (unsigned short*)(ws);
  unsigned short* w1t  = (unsigned short*)(ws + 33554432);
  unsigned short* w2t  = (unsigned short*)(ws + 41943040);
  unsigned short* wg1t = (unsigned short*)(ws + 50331648);
  unsigned short* wg2t = (unsigned short*)(ws + 52428800);
  unsigned short* hbuf = (unsigned short*)(ws + 54525952);
  unsigned short* rout = (unsigned short*)(ws + 62914560);
  int* offs  = (int*)(ws + 96468992);
  int* order = (int*)(ws + 96469248);
  int* tileE = (int*)(ws + 96485632);
  int* tileR = (int*)(ws + 96486208);
  int* ntl   = (int*)(ws + 96486784);

  prep_kernel<<<dim3(10752), 256, 0, stream>>>(x, xb, W1, w1t, W2, w2t, Wg1, wg1t, Wg2, wg2t);
  route_kernel<<<1, 256, 0, stream>>>(sid, S, offs, order, tileE, tileR, ntl);

  // GEMM1: h = gelu(gather(xb) @ W1[e] + b1[e])   [sorted rows, bf16]
  gemm_mfma<true, false, true, false><<<dim3(H / 128, 144), 256, 0, stream>>>(
      xb, w1t, b1, hbuf, H, D, order, offs, tileE, tileR, ntl, S, (long)H * D, H);
  // GEMM2: routed = h @ W2[e] + b2[e]             [scatter to natural rows, bf16]
  gemm_mfma<false, true, false, false><<<dim3(D / 128, 144), 256, 0, stream>>>(
      hbuf, w2t, b2, rout, D, H, order, offs, tileE, tileR, ntl, S, (long)D * H, D);
  // GEMM3: g = gelu(rout @ Wg1 + bg1)             [2-phase arm; writes xb region]
  gemm_2ph<true, false><<<dim3((unsigned)(NT / 256) * (D / 256)), 512, 0, stream>>>(
      rout, wg1t, bg1, xb, D, D, D / 256);
  // GEMM4: out = g @ Wg2 + bg2                    [8-phase arm; fp32 to d_out]
  gemm_8phase<false, true><<<dim3((unsigned)(NT / 256) * (D / 256)), 512, 0, stream>>>(
      xb, wg2t, bg2, d_out, D, D, D / 256);
}

// Round 10
// 182.756 us; speedup vs baseline: 1.2247x; 1.0207x over previous
//
#include <hip/hip_runtime.h>

// SplatAwareFeedForward on MI355X (gfx950).
// Pipeline: prep (x-cast + weight transposes) -> route (tile lists) ->
//           expert GEMM1/GEMM2 (m97-style, compact grids) ->
//           dense GEMM3/GEMM4 (m97 128x128 structure, 4 blocks/CU, XCD swizzle).
// Workspace layout (bytes):
//   xb    @ 0        : 33,554,432  (B*S*D bf16; reused as g-buffer for GEMM4 input)
//   w1t   @ 33554432 :  8,388,608  (E*[H][D] bf16, transposed W1)
//   w2t   @ 41943040 :  8,388,608  (E*[D][H] bf16, transposed W2)
//   wg1t  @ 50331648 :  2,097,152  ([D][D] bf16, transposed Wg1)
//   wg2t  @ 52428800 :  2,097,152  ([D][D] bf16, transposed Wg2)
//   hbuf  @ 54525952 :  8,388,608  (B*S*H bf16, expert-sorted hidden)
//   rout  @ 62914560 : 33,554,432  (B*S*D bf16, routed output, natural order)
//   offs  @ 96468992 : 68          (E+1 ints)
//   order @ 96469248 : 16,384      (S ints sorted by expert)
//   tileE @ 96485632 : 576         (expert id per 128-row tile, <=144)
//   tileR @ 96486208 : 576         (sorted-row start per tile)
//   ntl   @ 96486784 : 4           (tile count)

#define DEV __device__ __forceinline__

typedef float f32x4 __attribute__((ext_vector_type(4)));
typedef short short8 __attribute__((ext_vector_type(8)));

DEV unsigned short f2bf(float f) {
  unsigned u = __float_as_uint(f);
  u += 0x7fffu + ((u >> 16) & 1u);   // round-to-nearest-even
  return (unsigned short)(u >> 16);
}

DEV void gload16(const void* g, void* l) {
  __builtin_amdgcn_global_load_lds(
      (const __attribute__((address_space(1))) unsigned int*)g,
      (__attribute__((address_space(3))) unsigned int*)l, 16, 0, 0);
}

DEV float gelu_exact(float v) {
  return 0.5f * v * (1.0f + erff(v * 0.70710678118654752f));
}

// ---------------- prep: x-cast + all transpose-casts in ONE launch ----------------
__global__ __launch_bounds__(256) void prep_kernel(
    const float* __restrict__ x, unsigned short* __restrict__ xb,
    const float* __restrict__ W1, unsigned short* __restrict__ w1t,
    const float* __restrict__ W2, unsigned short* __restrict__ w2t,
    const float* __restrict__ Wg1, unsigned short* __restrict__ wg1t,
    const float* __restrict__ Wg2, unsigned short* __restrict__ wg2t) {
  __shared__ float tile[64][65];
  const int t = threadIdx.x;
  int id = (int)blockIdx.x;
  if (id < 8192) {
    long i = ((long)id * 256 + t) * 8;
    float4 v0 = *(const float4*)(x + i);
    float4 v1 = *(const float4*)(x + i + 4);
    uint4 o;
    o.x = (unsigned)f2bf(v0.x) | ((unsigned)f2bf(v0.y) << 16);
    o.y = (unsigned)f2bf(v0.z) | ((unsigned)f2bf(v0.w) << 16);
    o.z = (unsigned)f2bf(v1.x) | ((unsigned)f2bf(v1.y) << 16);
    o.w = (unsigned)f2bf(v1.z) | ((unsigned)f2bf(v1.w) << 16);
    *(uint4*)(xb + i) = o;
    return;
  }
  id -= 8192;
  const float* in; unsigned short* out;
  int R, C, r0, c0; long base;
  if (id < 1024) {          // W1: [1024][256] -> [256][1024] per expert
    in = W1; out = w1t; R = 1024; C = 256;
    base = (long)(id >> 6) * 262144;
    r0 = ((id >> 2) & 15) * 64; c0 = (id & 3) * 64;
  } else if (id < 2048) {   // W2: [256][1024] -> [1024][256] per expert
    id -= 1024;
    in = W2; out = w2t; R = 256; C = 1024;
    base = (long)(id >> 6) * 262144;
    r0 = ((id >> 4) & 3) * 64; c0 = (id & 15) * 64;
  } else if (id < 2304) {   // Wg1
    id -= 2048;
    in = Wg1; out = wg1t; R = 1024; C = 1024; base = 0;
    r0 = (id >> 4) * 64; c0 = (id & 15) * 64;
  } else {                  // Wg2
    id -= 2304;
    in = Wg2; out = wg2t; R = 1024; C = 1024; base = 0;
    r0 = (id >> 4) * 64; c0 = (id & 15) * 64;
  }
  const int cc = t & 63, rr = t >> 6;
#pragma unroll
  for (int i = 0; i < 16; i++) {
    int r = rr + i * 4;
    tile[r][cc] = in[base + (long)(r0 + r) * C + (c0 + cc)];
  }
  __syncthreads();
#pragma unroll
  for (int i = 0; i < 16; i++) {
    int c = rr + i * 4;
    out[base + (long)(c0 + c) * R + (r0 + cc)] = f2bf(tile[cc][c]);
  }
}

// ---------------- routing: counts -> prefix -> sorted order -> 128-row tile list ----------------
__global__ __launch_bounds__(256) void route_kernel(
    const int* __restrict__ sid, int S, int* __restrict__ offs, int* __restrict__ order,
    int* __restrict__ tileE, int* __restrict__ tileR, int* __restrict__ ntl) {
  __shared__ int cnt[16], cur[16];
  const int t = threadIdx.x;
  if (t < 16) cnt[t] = 0;
  __syncthreads();
  for (int s = t; s < S; s += 256) atomicAdd(&cnt[sid[s]], 1);
  __syncthreads();
  if (t == 0) {
    int a = 0;
    for (int e = 0; e < 16; e++) { offs[e] = a; cur[e] = a; a += cnt[e]; }
    offs[16] = a;
    int nt = 0;
    for (int e = 0; e < 16; e++) {
      const int rows = 4 * cnt[e];
      for (int r = 0; r < rows; r += 128) {
        tileE[nt] = e;
        tileR[nt] = 4 * offs[e] + r;
        nt++;
      }
    }
    ntl[0] = nt;
  }
  __syncthreads();
  for (int s = t; s < S; s += 256) {
    int p = atomicAdd(&cur[sid[s]], 1);
    order[p] = s;
  }
}

// ---------------- expert 128x128x64 bf16 MFMA GEMM (m97-style, compact tile grid) ----------------
template <bool GATHER_A, bool SCATTER_C, bool GELU, bool OUT_F32>
__global__ __launch_bounds__(256) void gemm_mfma(
    const unsigned short* __restrict__ A, const unsigned short* __restrict__ BT,
    const float* __restrict__ bias, void* __restrict__ Cout,
    int N, int K,
    const int* __restrict__ order, const int* __restrict__ offs,
    const int* __restrict__ tileE, const int* __restrict__ tileR,
    const int* __restrict__ ntl,
    int S, long btStride, int biasStride) {
  const int ti = (int)blockIdx.y;
  if (ti >= ntl[0]) return;
  const int t = (int)threadIdx.x;
  const int lane = t & 63;
  const int w = t >> 6;
  const int wm = w >> 1, wn = w & 1;
  const int tileN = (int)blockIdx.x;

  const int e = tileE[ti];
  const int rowBase = tileR[ti];
  int Me = 4 * offs[e + 1] - rowBase;
  if (Me > 128) Me = 128;
  const unsigned short* bt = BT + (long)e * btStride;
  const float* bs = bias + (long)e * biasStride;

  __shared__ __align__(16) unsigned short lA[128 * 64];
  __shared__ __align__(16) unsigned short lB[128 * 64];

  const unsigned short* aSrc[4];
  const unsigned short* bSrc[4];
  {
    const int q = t & 7;
#pragma unroll
    for (int i = 0; i < 4; i++) {
      const int row = i * 32 + (t >> 3);
      const int koff = ((q * 16) ^ ((row & 7) << 4)) >> 1;
      const int rr = (row < Me) ? row : (Me - 1);
      const int g = rowBase + rr;
      long arow;
      if (GATHER_A) {
        const int s = order[g >> 2];
        arow = (long)(g & 3) * S + s;
      } else {
        arow = g;
      }
      aSrc[i] = A + arow * (long)K + koff;
      const int col = tileN * 128 + row;
      bSrc[i] = bt + (long)col * K + koff;
    }
  }

  f32x4 acc[4][4] = {};

  const int KT = K >> 6;
  for (int kt = 0; kt < KT; kt++) {
    __syncthreads();
#pragma unroll
    for (int i = 0; i < 4; i++) {
      gload16(aSrc[i] + (kt << 6), (void*)(lA + i * 2048 + w * 512));
      gload16(bSrc[i] + (kt << 6), (void*)(lB + i * 2048 + w * 512));
    }
    __syncthreads();
#pragma unroll
    for (int kk = 0; kk < 2; kk++) {
      short8 af[4], bfr[4];
      const int kbyte = kk * 64 + (lane >> 4) * 16;
#pragma unroll
      for (int mi = 0; mi < 4; mi++) {
        const int row = wm * 64 + mi * 16 + (lane & 15);
        const int off = row * 128 + (kbyte ^ ((row & 7) << 4));
        af[mi] = *(const short8*)((const char*)lA + off);
      }
#pragma unroll
      for (int ni = 0; ni < 4; ni++) {
        const int row = wn * 64 + ni * 16 + (lane & 15);
        const int off = row * 128 + (kbyte ^ ((row & 7) << 4));
        bfr[ni] = *(const short8*)((const char*)lB + off);
      }
#pragma unroll
      for (int mi = 0; mi < 4; mi++)
#pragma unroll
        for (int ni = 0; ni < 4; ni++)
          acc[mi][ni] = __builtin_amdgcn_mfma_f32_16x16x32_bf16(af[mi], bfr[ni], acc[mi][ni], 0, 0, 0);
    }
  }

  float bcol[4];
#pragma unroll
  for (int ni = 0; ni < 4; ni++)
    bcol[ni] = bs[tileN * 128 + wn * 64 + ni * 16 + (lane & 15)];

#pragma unroll
  for (int mi = 0; mi < 4; mi++) {
#pragma unroll
    for (int j = 0; j < 4; j++) {
      const int lrow = wm * 64 + mi * 16 + ((lane >> 4) * 4) + j;
      if (lrow >= Me) continue;
      const int g = rowBase + lrow;
      long crow;
      if (SCATTER_C) crow = (long)(g & 3) * S + order[g >> 2];
      else crow = g;
#pragma unroll
      for (int ni = 0; ni < 4; ni++) {
        float v = acc[mi][ni][j] + bcol[ni];
        if (GELU) v = gelu_exact(v);
        const long cidx = crow * (long)N + tileN * 128 + wn * 64 + ni * 16 + (lane & 15);
        if (OUT_F32) ((float*)Cout)[cidx] = v;
        else ((unsigned short*)Cout)[cidx] = f2bf(v);
      }
    }
  }
}

// ---------------- dense 128x128x64 GEMM (m97 structure, 4 blocks/CU, XCD swizzle) ----------------
// C[M][N] = A[M][K] @ BT[N][K]^T (+bias, opt GELU). 256 threads = 4 waves (2Mx2N),
// per-wave 64x64. Single-buffered 32KB LDS, 2 barriers per K-step (m97 exact).
// Occupancy: 32KB LDS -> up to 5 blocks/CU; VGPR ~80 -> 4 resident. Inter-block
// wave overlap hides the per-block barrier drain (m114 mechanism).
// Grid = mtiles*ntiles (multiple of 8); XCD-chunked swizzle, ntile-fastest.
template <bool GELU, bool OUT_F32>
__global__ __launch_bounds__(256, 4) void gemm_dense128(
    const unsigned short* __restrict__ A, const unsigned short* __restrict__ BT,
    const float* __restrict__ bias, void* __restrict__ Cout,
    int N, int K, int ntiles) {
  const int t = (int)threadIdx.x;
  const int lane = t & 63;
  const int w = t >> 6;
  const int wm = w >> 1, wn = w & 1;

  const int cpx = (int)gridDim.x >> 3;
  const int swz = ((int)blockIdx.x & 7) * cpx + ((int)blockIdx.x >> 3);
  const int mtile = swz / ntiles, ntile = swz % ntiles;

  __shared__ __align__(16) unsigned short lA[128 * 64];
  __shared__ __align__(16) unsigned short lB[128 * 64];

  const unsigned short* aSrc[4];
  const unsigned short* bSrc[4];
  {
    const int q = t & 7;
#pragma unroll
    for (int i = 0; i < 4; i++) {
      const int row = i * 32 + (t >> 3);
      const int koff = ((q * 16) ^ ((row & 7) << 4)) >> 1;
      aSrc[i] = A + (long)(mtile * 128 + row) * K + koff;
      bSrc[i] = BT + (long)(ntile * 128 + row) * K + koff;
    }
  }

  f32x4 acc[4][4] = {};

  const int KT = K >> 6;
  for (int kt = 0; kt < KT; kt++) {
    __syncthreads();
#pragma unroll
    for (int i = 0; i < 4; i++) {
      gload16(aSrc[i] + (kt << 6), (void*)(lA + i * 2048 + w * 512));
      gload16(bSrc[i] + (kt << 6), (void*)(lB + i * 2048 + w * 512));
    }
    __syncthreads();
#pragma unroll
    for (int kk = 0; kk < 2; kk++) {
      short8 af[4], bfr[4];
      const int kbyte = kk * 64 + (lane >> 4) * 16;
#pragma unroll
      for (int mi = 0; mi < 4; mi++) {
        const int row = wm * 64 + mi * 16 + (lane & 15);
        const int off = row * 128 + (kbyte ^ ((row & 7) << 4));
        af[mi] = *(const short8*)((const char*)lA + off);
      }
#pragma unroll
      for (int ni = 0; ni < 4; ni++) {
        const int row = wn * 64 + ni * 16 + (lane & 15);
        const int off = row * 128 + (kbyte ^ ((row & 7) << 4));
        bfr[ni] = *(const short8*)((const char*)lB + off);
      }
#pragma unroll
      for (int mi = 0; mi < 4; mi++)
#pragma unroll
        for (int ni = 0; ni < 4; ni++)
          acc[mi][ni] = __builtin_amdgcn_mfma_f32_16x16x32_bf16(af[mi], bfr[ni], acc[mi][ni], 0, 0, 0);
    }
  }

  float bcol[4];
#pragma unroll
  for (int ni = 0; ni < 4; ni++)
    bcol[ni] = bias[ntile * 128 + wn * 64 + ni * 16 + (lane & 15)];

#pragma unroll
  for (int mi = 0; mi < 4; mi++) {
#pragma unroll
    for (int j = 0; j < 4; j++) {
      const long crow = mtile * 128 + wm * 64 + mi * 16 + ((lane >> 4) * 4) + j;
#pragma unroll
      for (int ni = 0; ni < 4; ni++) {
        float v = acc[mi][ni][j] + bcol[ni];
        if (GELU) v = gelu_exact(v);
        const long cidx = crow * (long)N + ntile * 128 + wn * 64 + ni * 16 + (lane & 15);
        if (OUT_F32) ((float*)Cout)[cidx] = v;
        else ((unsigned short*)Cout)[cidx] = f2bf(v);
      }
    }
  }
}

extern "C" void kernel_launch(void* const* d_in, const int* in_sizes, int n_in,
                              void* d_out, int out_size, void* d_ws, size_t ws_size,
                              hipStream_t stream) {
  const float* x   = (const float*)d_in[0];
  const int*   sid = (const int*)d_in[1];
  const float* W1  = (const float*)d_in[2];
  const float* b1  = (const float*)d_in[3];
  const float* W2  = (const float*)d_in[4];
  const float* b2  = (const float*)d_in[5];
  const float* Wg1 = (const float*)d_in[6];
  const float* bg1 = (const float*)d_in[7];
  const float* Wg2 = (const float*)d_in[8];
  const float* bg2 = (const float*)d_in[9];
  (void)in_sizes; (void)n_in; (void)out_size; (void)ws_size;

  constexpr int D = 1024, H = 256, S = 4096, B = 4;
  constexpr long NT = (long)B * S;  // 16384 token rows

  char* ws = (char*)d_ws;
  unsigned short* xb   = (unsigned short*)(ws);
  unsigned short* w1t  = (unsigned short*)(ws + 33554432);
  unsigned short* w2t  = (unsigned short*)(ws + 41943040);
  unsigned short* wg1t = (unsigned short*)(ws + 50331648);
  unsigned short* wg2t = (unsigned short*)(ws + 52428800);
  unsigned short* hbuf = (unsigned short*)(ws + 54525952);
  unsigned short* rout = (unsigned short*)(ws + 62914560);
  int* offs  = (int*)(ws + 96468992);
  int* order = (int*)(ws + 96469248);
  int* tileE = (int*)(ws + 96485632);
  int* tileR = (int*)(ws + 96486208);
  int* ntl   = (int*)(ws + 96486784);

  prep_kernel<<<dim3(10752), 256, 0, stream>>>(x, xb, W1, w1t, W2, w2t, Wg1, wg1t, Wg2, wg2t);
  route_kernel<<<1, 256, 0, stream>>>(sid, S, offs, order, tileE, tileR, ntl);

  // GEMM1: h = gelu(gather(xb) @ W1[e] + b1[e])   [sorted rows, bf16]
  gemm_mfma<true, false, true, false><<<dim3(H / 128, 144), 256, 0, stream>>>(
      xb, w1t, b1, hbuf, H, D, order, offs, tileE, tileR, ntl, S, (long)H * D, H);
  // GEMM2: routed = h @ W2[e] + b2[e]             [scatter to natural rows, bf16]
  gemm_mfma<false, true, false, false><<<dim3(D / 128, 144), 256, 0, stream>>>(
      hbuf, w2t, b2, rout, D, H, order, offs, tileE, tileR, ntl, S, (long)D * H, D);
  // GEMM3: g = gelu(rout @ Wg1 + bg1)   [128-tile m97 structure, 1024 blocks]
  gemm_dense128<true, false><<<dim3((unsigned)(NT / 128) * (D / 128)), 256, 0, stream>>>(
      rout, wg1t, bg1, xb, D, D, D / 128);
  // GEMM4: out = g @ Wg2 + bg2          [fp32 to d_out]
  gemm_dense128<false, true><<<dim3((unsigned)(NT / 128) * (D / 128)), 256, 0, stream>>>(
      xb, wg2t, bg2, d_out, D, D, D / 128);
}

// Round 12
// 181.252 us; speedup vs baseline: 1.2348x; 1.0083x over previous
//
#include <hip/hip_runtime.h>

// SplatAwareFeedForward on MI355X (gfx950).
// Pipeline: prep (weight transposes only) -> route (64- and 128-row tile lists) ->
//           GEMM1 (gather+cast f32 x, 64x128 tiles) -> GEMM2 (m97-style) ->
//           dense GEMM3/GEMM4 (m97 128x128, 4 blocks/CU, XCD swizzle).
// Workspace layout (bytes):
//   gbuf  @ 0        : 33,554,432  (B*S*D bf16; dense g-buffer GEMM3 out / GEMM4 in)
//   w1t   @ 33554432 :  8,388,608  (E*[H][D] bf16, transposed W1)
//   w2t   @ 41943040 :  8,388,608  (E*[D][H] bf16, transposed W2)
//   wg1t  @ 50331648 :  2,097,152  ([D][D] bf16, transposed Wg1)
//   wg2t  @ 52428800 :  2,097,152  ([D][D] bf16, transposed Wg2)
//   hbuf  @ 54525952 :  8,388,608  (B*S*H bf16, expert-sorted hidden)
//   rout  @ 62914560 : 33,554,432  (B*S*D bf16, routed output, natural order)
//   offs  @ 96468992 : 68          (E+1 ints)
//   order @ 96469248 : 16,384      (S ints sorted by expert)
//   tileE @ 96485632 : 576         (expert id per 128-row tile, <=144)
//   tileR @ 96486208 : 576         (sorted-row start per 128-row tile)
//   ntl   @ 96486784 : 4           (128-row tile count)
//   t64E  @ 96487424 : 1,152       (expert id per 64-row tile, <=272)
//   t64R  @ 96488704 : 1,152       (sorted-row start per 64-row tile)
//   ntl64 @ 96489984 : 4           (64-row tile count)

#define DEV __device__ __forceinline__

typedef float f32x4 __attribute__((ext_vector_type(4)));
typedef short short8 __attribute__((ext_vector_type(8)));

DEV unsigned short f2bf(float f) {
  unsigned u = __float_as_uint(f);
  u += 0x7fffu + ((u >> 16) & 1u);   // round-to-nearest-even
  return (unsigned short)(u >> 16);
}

DEV void gload16(const void* g, void* l) {
  __builtin_amdgcn_global_load_lds(
      (const __attribute__((address_space(1))) unsigned int*)g,
      (__attribute__((address_space(3))) unsigned int*)l, 16, 0, 0);
}

DEV float gelu_exact(float v) {
  return 0.5f * v * (1.0f + erff(v * 0.70710678118654752f));
}

// ---------------- prep: weight transpose-casts ONLY (x-cast eliminated) ----------------
// blocks [0,1024): W1; [1024,2048): W2; [2048,2304): Wg1; [2304,2560): Wg2
__global__ __launch_bounds__(256) void prep_kernel(
    const float* __restrict__ W1, unsigned short* __restrict__ w1t,
    const float* __restrict__ W2, unsigned short* __restrict__ w2t,
    const float* __restrict__ Wg1, unsigned short* __restrict__ wg1t,
    const float* __restrict__ Wg2, unsigned short* __restrict__ wg2t) {
  __shared__ float tile[64][65];
  const int t = threadIdx.x;
  int id = (int)blockIdx.x;
  const float* in; unsigned short* out;
  int R, C, r0, c0; long base;
  if (id < 1024) {          // W1: [1024][256] -> [256][1024] per expert
    in = W1; out = w1t; R = 1024; C = 256;
    base = (long)(id >> 6) * 262144;
    r0 = ((id >> 2) & 15) * 64; c0 = (id & 3) * 64;
  } else if (id < 2048) {   // W2: [256][1024] -> [1024][256] per expert
    id -= 1024;
    in = W2; out = w2t; R = 256; C = 1024;
    base = (long)(id >> 6) * 262144;
    r0 = ((id >> 4) & 3) * 64; c0 = (id & 15) * 64;
  } else if (id < 2304) {   // Wg1
    id -= 2048;
    in = Wg1; out = wg1t; R = 1024; C = 1024; base = 0;
    r0 = (id >> 4) * 64; c0 = (id & 15) * 64;
  } else {                  // Wg2
    id -= 2304;
    in = Wg2; out = wg2t; R = 1024; C = 1024; base = 0;
    r0 = (id >> 4) * 64; c0 = (id & 15) * 64;
  }
  const int cc = t & 63, rr = t >> 6;
#pragma unroll
  for (int i = 0; i < 16; i++) {
    int r = rr + i * 4;
    tile[r][cc] = in[base + (long)(r0 + r) * C + (c0 + cc)];
  }
  __syncthreads();
#pragma unroll
  for (int i = 0; i < 16; i++) {
    int c = rr + i * 4;
    out[base + (long)(c0 + c) * R + (r0 + cc)] = f2bf(tile[cc][c]);
  }
}

// ---------------- routing: sorted order + 128-row and 64-row tile lists ----------------
__global__ __launch_bounds__(256) void route_kernel(
    const int* __restrict__ sid, int S, int* __restrict__ offs, int* __restrict__ order,
    int* __restrict__ tileE, int* __restrict__ tileR, int* __restrict__ ntl,
    int* __restrict__ t64E, int* __restrict__ t64R, int* __restrict__ ntl64) {
  __shared__ int cnt[16], cur[16];
  const int t = threadIdx.x;
  if (t < 16) cnt[t] = 0;
  __syncthreads();
  for (int s = t; s < S; s += 256) atomicAdd(&cnt[sid[s]], 1);
  __syncthreads();
  if (t == 0) {
    int a = 0;
    for (int e = 0; e < 16; e++) { offs[e] = a; cur[e] = a; a += cnt[e]; }
    offs[16] = a;
    int nt = 0, n64 = 0;
    for (int e = 0; e < 16; e++) {
      const int rows = 4 * cnt[e];
      for (int r = 0; r < rows; r += 128) {
        tileE[nt] = e; tileR[nt] = 4 * offs[e] + r; nt++;
      }
      for (int r = 0; r < rows; r += 64) {
        t64E[n64] = e; t64R[n64] = 4 * offs[e] + r; n64++;
      }
    }
    ntl[0] = nt;
    ntl64[0] = n64;
  }
  __syncthreads();
  for (int s = t; s < S; s += 256) {
    int p = atomicAdd(&cur[sid[s]], 1);
    order[p] = s;
  }
}

// ---------------- GEMM1: h = gelu(gather(x,f32) @ W1[e] + b1[e]), 64x128 tiles ----------------
// A gathered from f32 x (cast in regs, ds_write to swizzled-linear LDS); B via gload16.
// 256 threads = 4 waves along N (per-wave 64x32). LDS 24KB -> multi-block/CU.
// B staging: 256 threads -> 4 issues x 32 rows (i*32 + (t>>3)), dst lB + i*2048 + dstE.
// (Round-11 bug: 2-issue/64-row pattern needs 512 threads; left rows 32-63/96-127 unstaged.)
__global__ __launch_bounds__(256, 4) void gemm_g1(
    const float* __restrict__ x,
    const unsigned short* __restrict__ w1t, const float* __restrict__ b1,
    unsigned short* __restrict__ hbuf,
    const int* __restrict__ order, const int* __restrict__ offs,
    const int* __restrict__ t64E, const int* __restrict__ t64R,
    const int* __restrict__ ntl64) {
  constexpr int S = 4096, D = 1024, H = 256;
  const int ti = (int)blockIdx.y;
  if (ti >= ntl64[0]) return;
  const int ntile = (int)blockIdx.x;   // 0..1 (128-col block of H=256)
  const int t = (int)threadIdx.x;
  const int lane = t & 63;
  const int wn = t >> 6;               // 0..3

  const int e = t64E[ti];
  const int rowBase = t64R[ti];
  int Me = 4 * offs[e + 1] - rowBase;
  if (Me > 64) Me = 64;

  __shared__ __align__(16) unsigned short lA[64 * 64];    // 8KB
  __shared__ __align__(16) unsigned short lB[128 * 64];   // 16KB

  // A gather sources (2 groups x 32 rows), swizzle pre-applied to source column.
  const float* xsrc[2];
  int aDst[2];
#pragma unroll
  for (int i = 0; i < 2; i++) {
    const int row = i * 32 + (t >> 3);
    const int koff = (((t & 7) * 16) ^ ((row & 7) << 4)) >> 1;   // logical elem col 0..56
    const int rr = (row < Me) ? row : (Me - 1);
    const int g = rowBase + rr;
    xsrc[i] = x + ((long)(g & 3) * S + order[g >> 2]) * D + koff;
    aDst[i] = row * 64 + (t & 7) * 8;
  }
  // B: w1t[e] is [H=256][D=1024]; 4 issues x 32 rows (256-thread staging pattern).
  const unsigned short* bSrc[4];
#pragma unroll
  for (int i = 0; i < 4; i++) {
    const int row = i * 32 + (t >> 3);
    bSrc[i] = w1t + (long)e * H * D + (long)(ntile * 128 + row) * D +
              ((((t & 7) * 16) ^ ((row & 7) << 4)) >> 1);
  }
  const int dstE = (t >> 3) * 64 + (t & 7) * 8;   // = wave-uniform + lane*16B

  f32x4 acc[4][2] = {};
  float4 xv[2][2];
#pragma unroll
  for (int i = 0; i < 2; i++) {
    xv[i][0] = *(const float4*)(xsrc[i]);
    xv[i][1] = *(const float4*)(xsrc[i] + 4);
  }

  for (int kt = 0; kt < 16; kt++) {
    __syncthreads();                   // prev compute done reading lA/lB
#pragma unroll
    for (int i = 0; i < 2; i++) {
      short8 av;
      av[0] = (short)f2bf(xv[i][0].x); av[1] = (short)f2bf(xv[i][0].y);
      av[2] = (short)f2bf(xv[i][0].z); av[3] = (short)f2bf(xv[i][0].w);
      av[4] = (short)f2bf(xv[i][1].x); av[5] = (short)f2bf(xv[i][1].y);
      av[6] = (short)f2bf(xv[i][1].z); av[7] = (short)f2bf(xv[i][1].w);
      *(short8*)(lA + aDst[i]) = av;
    }
#pragma unroll
    for (int i = 0; i < 4; i++)
      gload16(bSrc[i] + (kt << 6), lB + i * 2048 + dstE);
    if (kt < 15) {
#pragma unroll
      for (int i = 0; i < 2; i++) {
        xv[i][0] = *(const float4*)(xsrc[i] + (kt + 1) * 64);
        xv[i][1] = *(const float4*)(xsrc[i] + (kt + 1) * 64 + 4);
      }
    }
    __syncthreads();                   // lA written + lB staged
#pragma unroll
    for (int kk = 0; kk < 2; kk++) {
      short8 aF[4], bF[2];
      const int kb = kk * 64 + ((lane >> 4) << 4);
#pragma unroll
      for (int mi = 0; mi < 4; mi++) {
        const int row = mi * 16 + (lane & 15);
        aF[mi] = *(const short8*)((const char*)lA + row * 128 + (kb ^ ((row & 7) << 4)));
      }
#pragma unroll
      for (int ni = 0; ni < 2; ni++) {
        const int row = wn * 32 + ni * 16 + (lane & 15);
        bF[ni] = *(const short8*)((const char*)lB + row * 128 + (kb ^ ((row & 7) << 4)));
      }
#pragma unroll
      for (int mi = 0; mi < 4; mi++)
#pragma unroll
        for (int ni = 0; ni < 2; ni++)
          acc[mi][ni] = __builtin_amdgcn_mfma_f32_16x16x32_bf16(aF[mi], bF[ni], acc[mi][ni], 0, 0, 0);
    }
  }

  float bc[2];
#pragma unroll
  for (int ni = 0; ni < 2; ni++)
    bc[ni] = b1[e * H + ntile * 128 + wn * 32 + ni * 16 + (lane & 15)];
#pragma unroll
  for (int mi = 0; mi < 4; mi++)
#pragma unroll
    for (int j = 0; j < 4; j++) {
      const int lrow = mi * 16 + ((lane >> 4) << 2) + j;
      if (lrow >= Me) continue;
      const long crow = rowBase + lrow;
#pragma unroll
      for (int ni = 0; ni < 2; ni++) {
        const float v = gelu_exact(acc[mi][ni][j] + bc[ni]);
        hbuf[crow * H + ntile * 128 + wn * 32 + ni * 16 + (lane & 15)] = f2bf(v);
      }
    }
}

// ---------------- GEMM2: expert 128x128x64 (m97-style, compact tile grid) ----------------
__global__ __launch_bounds__(256) void gemm_g2(
    const unsigned short* __restrict__ A, const unsigned short* __restrict__ BT,
    const float* __restrict__ bias, unsigned short* __restrict__ Cout,
    int N, int K,
    const int* __restrict__ order, const int* __restrict__ offs,
    const int* __restrict__ tileE, const int* __restrict__ tileR,
    const int* __restrict__ ntl,
    int S, long btStride, int biasStride) {
  const int ti = (int)blockIdx.y;
  if (ti >= ntl[0]) return;
  const int t = (int)threadIdx.x;
  const int lane = t & 63;
  const int w = t >> 6;
  const int wm = w >> 1, wn = w & 1;
  const int tileN = (int)blockIdx.x;

  const int e = tileE[ti];
  const int rowBase = tileR[ti];
  int Me = 4 * offs[e + 1] - rowBase;
  if (Me > 128) Me = 128;
  const unsigned short* bt = BT + (long)e * btStride;
  const float* bs = bias + (long)e * biasStride;

  __shared__ __align__(16) unsigned short lA[128 * 64];
  __shared__ __align__(16) unsigned short lB[128 * 64];

  const unsigned short* aSrc[4];
  const unsigned short* bSrc[4];
  {
    const int q = t & 7;
#pragma unroll
    for (int i = 0; i < 4; i++) {
      const int row = i * 32 + (t >> 3);
      const int koff = ((q * 16) ^ ((row & 7) << 4)) >> 1;
      const int rr = (row < Me) ? row : (Me - 1);
      const int g = rowBase + rr;
      aSrc[i] = A + (long)g * K + koff;
      const int col = tileN * 128 + row;
      bSrc[i] = bt + (long)col * K + koff;
    }
  }

  f32x4 acc[4][4] = {};

  const int KT = K >> 6;
  for (int kt = 0; kt < KT; kt++) {
    __syncthreads();
#pragma unroll
    for (int i = 0; i < 4; i++) {
      gload16(aSrc[i] + (kt << 6), (void*)(lA + i * 2048 + w * 512));
      gload16(bSrc[i] + (kt << 6), (void*)(lB + i * 2048 + w * 512));
    }
    __syncthreads();
#pragma unroll
    for (int kk = 0; kk < 2; kk++) {
      short8 af[4], bfr[4];
      const int kbyte = kk * 64 + (lane >> 4) * 16;
#pragma unroll
      for (int mi = 0; mi < 4; mi++) {
        const int row = wm * 64 + mi * 16 + (lane & 15);
        const int off = row * 128 + (kbyte ^ ((row & 7) << 4));
        af[mi] = *(const short8*)((const char*)lA + off);
      }
#pragma unroll
      for (int ni = 0; ni < 4; ni++) {
        const int row = wn * 64 + ni * 16 + (lane & 15);
        const int off = row * 128 + (kbyte ^ ((row & 7) << 4));
        bfr[ni] = *(const short8*)((const char*)lB + off);
      }
#pragma unroll
      for (int mi = 0; mi < 4; mi++)
#pragma unroll
        for (int ni = 0; ni < 4; ni++)
          acc[mi][ni] = __builtin_amdgcn_mfma_f32_16x16x32_bf16(af[mi], bfr[ni], acc[mi][ni], 0, 0, 0);
    }
  }

  float bcol[4];
#pragma unroll
  for (int ni = 0; ni < 4; ni++)
    bcol[ni] = bs[tileN * 128 + wn * 64 + ni * 16 + (lane & 15)];

#pragma unroll
  for (int mi = 0; mi < 4; mi++) {
#pragma unroll
    for (int j = 0; j < 4; j++) {
      const int lrow = wm * 64 + mi * 16 + ((lane >> 4) * 4) + j;
      if (lrow >= Me) continue;
      const int g = rowBase + lrow;
      const long crow = (long)(g & 3) * S + order[g >> 2];   // scatter to natural rows
#pragma unroll
      for (int ni = 0; ni < 4; ni++) {
        const float v = acc[mi][ni][j] + bcol[ni];
        Cout[crow * (long)N + tileN * 128 + wn * 64 + ni * 16 + (lane & 15)] = f2bf(v);
      }
    }
  }
}

// ---------------- dense 128x128x64 GEMM (m97 structure, 4 blocks/CU, XCD swizzle) ----------------
template <bool GELU, bool OUT_F32>
__global__ __launch_bounds__(256, 4) void gemm_dense128(
    const unsigned short* __restrict__ A, const unsigned short* __restrict__ BT,
    const float* __restrict__ bias, void* __restrict__ Cout,
    int N, int K, int ntiles) {
  const int t = (int)threadIdx.x;
  const int lane = t & 63;
  const int w = t >> 6;
  const int wm = w >> 1, wn = w & 1;

  const int cpx = (int)gridDim.x >> 3;
  const int swz = ((int)blockIdx.x & 7) * cpx + ((int)blockIdx.x >> 3);
  const int mtile = swz / ntiles, ntile = swz % ntiles;

  __shared__ __align__(16) unsigned short lA[128 * 64];
  __shared__ __align__(16) unsigned short lB[128 * 64];

  const unsigned short* aSrc[4];
  const unsigned short* bSrc[4];
  {
    const int q = t & 7;
#pragma unroll
    for (int i = 0; i < 4; i++) {
      const int row = i * 32 + (t >> 3);
      const int koff = ((q * 16) ^ ((row & 7) << 4)) >> 1;
      aSrc[i] = A + (long)(mtile * 128 + row) * K + koff;
      bSrc[i] = BT + (long)(ntile * 128 + row) * K + koff;
    }
  }

  f32x4 acc[4][4] = {};

  const int KT = K >> 6;
  for (int kt = 0; kt < KT; kt++) {
    __syncthreads();
#pragma unroll
    for (int i = 0; i < 4; i++) {
      gload16(aSrc[i] + (kt << 6), (void*)(lA + i * 2048 + w * 512));
      gload16(bSrc[i] + (kt << 6), (void*)(lB + i * 2048 + w * 512));
    }
    __syncthreads();
#pragma unroll
    for (int kk = 0; kk < 2; kk++) {
      short8 af[4], bfr[4];
      const int kbyte = kk * 64 + (lane >> 4) * 16;
#pragma unroll
      for (int mi = 0; mi < 4; mi++) {
        const int row = wm * 64 + mi * 16 + (lane & 15);
        const int off = row * 128 + (kbyte ^ ((row & 7) << 4));
        af[mi] = *(const short8*)((const char*)lA + off);
      }
#pragma unroll
      for (int ni = 0; ni < 4; ni++) {
        const int row = wn * 64 + ni * 16 + (lane & 15);
        const int off = row * 128 + (kbyte ^ ((row & 7) << 4));
        bfr[ni] = *(const short8*)((const char*)lB + off);
      }
#pragma unroll
      for (int mi = 0; mi < 4; mi++)
#pragma unroll
        for (int ni = 0; ni < 4; ni++)
          acc[mi][ni] = __builtin_amdgcn_mfma_f32_16x16x32_bf16(af[mi], bfr[ni], acc[mi][ni], 0, 0, 0);
    }
  }

  float bcol[4];
#pragma unroll
  for (int ni = 0; ni < 4; ni++)
    bcol[ni] = bias[ntile * 128 + wn * 64 + ni * 16 + (lane & 15)];

#pragma unroll
  for (int mi = 0; mi < 4; mi++) {
#pragma unroll
    for (int j = 0; j < 4; j++) {
      const long crow = mtile * 128 + wm * 64 + mi * 16 + ((lane >> 4) * 4) + j;
#pragma unroll
      for (int ni = 0; ni < 4; ni++) {
        float v = acc[mi][ni][j] + bcol[ni];
        if (GELU) v = gelu_exact(v);
        const long cidx = crow * (long)N + ntile * 128 + wn * 64 + ni * 16 + (lane & 15);
        if (OUT_F32) ((float*)Cout)[cidx] = v;
        else ((unsigned short*)Cout)[cidx] = f2bf(v);
      }
    }
  }
}

extern "C" void kernel_launch(void* const* d_in, const int* in_sizes, int n_in,
                              void* d_out, int out_size, void* d_ws, size_t ws_size,
                              hipStream_t stream) {
  const float* x   = (const float*)d_in[0];
  const int*   sid = (const int*)d_in[1];
  const float* W1  = (const float*)d_in[2];
  const float* b1  = (const float*)d_in[3];
  const float* W2  = (const float*)d_in[4];
  const float* b2  = (const float*)d_in[5];
  const float* Wg1 = (const float*)d_in[6];
  const float* bg1 = (const float*)d_in[7];
  const float* Wg2 = (const float*)d_in[8];
  const float* bg2 = (const float*)d_in[9];
  (void)in_sizes; (void)n_in; (void)out_size; (void)ws_size;

  constexpr int D = 1024, H = 256, S = 4096, B = 4;
  constexpr long NT = (long)B * S;  // 16384 token rows

  char* ws = (char*)d_ws;
  unsigned short* gbuf = (unsigned short*)(ws);
  unsigned short* w1t  = (unsigned short*)(ws + 33554432);
  unsigned short* w2t  = (unsigned short*)(ws + 41943040);
  unsigned short* wg1t = (unsigned short*)(ws + 50331648);
  unsigned short* wg2t = (unsigned short*)(ws + 52428800);
  unsigned short* hbuf = (unsigned short*)(ws + 54525952);
  unsigned short* rout = (unsigned short*)(ws + 62914560);
  int* offs  = (int*)(ws + 96468992);
  int* order = (int*)(ws + 96469248);
  int* tileE = (int*)(ws + 96485632);
  int* tileR = (int*)(ws + 96486208);
  int* ntl   = (int*)(ws + 96486784);
  int* t64E  = (int*)(ws + 96487424);
  int* t64R  = (int*)(ws + 96488704);
  int* ntl64 = (int*)(ws + 96489984);

  prep_kernel<<<dim3(2560), 256, 0, stream>>>(W1, w1t, W2, w2t, Wg1, wg1t, Wg2, wg2t);
  route_kernel<<<1, 256, 0, stream>>>(sid, S, offs, order, tileE, tileR, ntl, t64E, t64R, ntl64);

  // GEMM1: h = gelu(gather(x,f32) @ W1[e] + b1[e])  [64x128 tiles, ~544 blocks]
  gemm_g1<<<dim3(H / 128, 272), 256, 0, stream>>>(
      x, w1t, b1, hbuf, order, offs, t64E, t64R, ntl64);
  // GEMM2: routed = h @ W2[e] + b2[e]               [scatter to natural rows]
  gemm_g2<<<dim3(D / 128, 144), 256, 0, stream>>>(
      hbuf, w2t, b2, rout, D, H, order, offs, tileE, tileR, ntl, S, (long)D * H, D);
  // GEMM3: g = gelu(rout @ Wg1 + bg1)               [m97 128-tile, 1024 blocks]
  gemm_dense128<true, false><<<dim3((unsigned)(NT / 128) * (D / 128)), 256, 0, stream>>>(
      rout, wg1t, bg1, gbuf, D, D, D / 128);
  // GEMM4: out = g @ Wg2 + bg2                      [fp32 to d_out]
  gemm_dense128<false, true><<<dim3((unsigned)(NT / 128) * (D / 128)), 256, 0, stream>>>(
      gbuf, wg2t, bg2, d_out, D, D, D / 128);
}

// Round 13
// 179.626 us; speedup vs baseline: 1.2460x; 1.0091x over previous
//
#include <hip/hip_runtime.h>

// SplatAwareFeedForward on MI355X (gfx950).
// Pipeline: route -> merged prep (weight transposes + sorted gather-cast of x) ->
//           expert GEMM1/GEMM2 (m97 128x128, compact tile list, 4 blocks/CU) ->
//           dense GEMM3/GEMM4 (m97 128x128, 4 blocks/CU, XCD swizzle).
// Workspace layout (bytes):
//   xg/gbuf @ 0        : 33,554,432  (sorted x bf16 for G1; later reused as dense g-buffer)
//   w1t   @ 33554432 :  8,388,608  (E*[H][D] bf16, transposed W1)
//   w2t   @ 41943040 :  8,388,608  (E*[D][H] bf16, transposed W2)
//   wg1t  @ 50331648 :  2,097,152  ([D][D] bf16, transposed Wg1)
//   wg2t  @ 52428800 :  2,097,152  ([D][D] bf16, transposed Wg2)
//   hbuf  @ 54525952 :  8,388,608  (B*S*H bf16, expert-sorted hidden)
//   rout  @ 62914560 : 33,554,432  (B*S*D bf16, routed output, natural order)
//   offs  @ 96468992 : 68          (E+1 ints)
//   order @ 96469248 : 16,384      (S ints sorted by expert)
//   tileE @ 96485632 : 576         (expert id per 128-row tile, <=144)
//   tileR @ 96486208 : 576         (sorted-row start per 128-row tile)
//   ntl   @ 96486784 : 4           (tile count)

#define DEV __device__ __forceinline__

typedef float f32x4 __attribute__((ext_vector_type(4)));
typedef short short8 __attribute__((ext_vector_type(8)));

DEV unsigned short f2bf(float f) {
  unsigned u = __float_as_uint(f);
  u += 0x7fffu + ((u >> 16) & 1u);   // round-to-nearest-even
  return (unsigned short)(u >> 16);
}

DEV void gload16(const void* g, void* l) {
  __builtin_amdgcn_global_load_lds(
      (const __attribute__((address_space(1))) unsigned int*)g,
      (__attribute__((address_space(3))) unsigned int*)l, 16, 0, 0);
}

DEV float gelu_exact(float v) {
  return 0.5f * v * (1.0f + erff(v * 0.70710678118654752f));
}

// ---------------- routing: sorted order + 128-row tile list (runs FIRST) ----------------
__global__ __launch_bounds__(256) void route_kernel(
    const int* __restrict__ sid, int S, int* __restrict__ offs, int* __restrict__ order,
    int* __restrict__ tileE, int* __restrict__ tileR, int* __restrict__ ntl) {
  __shared__ int cnt[16], cur[16];
  const int t = threadIdx.x;
  if (t < 16) cnt[t] = 0;
  __syncthreads();
  for (int s = t; s < S; s += 256) atomicAdd(&cnt[sid[s]], 1);
  __syncthreads();
  if (t == 0) {
    int a = 0;
    for (int e = 0; e < 16; e++) { offs[e] = a; cur[e] = a; a += cnt[e]; }
    offs[16] = a;
    int nt = 0;
    for (int e = 0; e < 16; e++) {
      const int rows = 4 * cnt[e];
      for (int r = 0; r < rows; r += 128) {
        tileE[nt] = e; tileR[nt] = 4 * offs[e] + r; nt++;
      }
    }
    ntl[0] = nt;
  }
  __syncthreads();
  for (int s = t; s < S; s += 256) {
    int p = atomicAdd(&cur[sid[s]], 1);
    order[p] = s;
  }
}

// ---------------- merged prep: weight transposes + sorted gather-cast of x ----------------
// blocks [0,1024): W1; [1024,2048): W2; [2048,2304): Wg1; [2304,2560): Wg2;
// blocks [2560,10752): gather-cast — block g handles sorted rows 2g, 2g+1:
//   xg[p][0:1024] = bf16(x[(p&3)*S + order[p>>2]][0:1024]).  Coalesced both sides.
__global__ __launch_bounds__(256) void prep_kernel(
    const float* __restrict__ x, const int* __restrict__ order,
    unsigned short* __restrict__ xg,
    const float* __restrict__ W1, unsigned short* __restrict__ w1t,
    const float* __restrict__ W2, unsigned short* __restrict__ w2t,
    const float* __restrict__ Wg1, unsigned short* __restrict__ wg1t,
    const float* __restrict__ Wg2, unsigned short* __restrict__ wg2t) {
  const int t = threadIdx.x;
  int id = (int)blockIdx.x;
  if (id >= 2560) {                       // gather-cast
    const int gid = id - 2560;            // 0..8191
    const int local = t * 8;              // 0..2040
    const int rl = local >> 10;           // 0 or 1
    const int col = local & 1023;
    const int p = 2 * gid + rl;           // sorted row 0..16383
    const long srcrow = (long)(p & 3) * 4096 + order[p >> 2];
    const float* src = x + srcrow * 1024 + col;
    float4 v0 = *(const float4*)(src);
    float4 v1 = *(const float4*)(src + 4);
    uint4 o;
    o.x = (unsigned)f2bf(v0.x) | ((unsigned)f2bf(v0.y) << 16);
    o.y = (unsigned)f2bf(v0.z) | ((unsigned)f2bf(v0.w) << 16);
    o.z = (unsigned)f2bf(v1.x) | ((unsigned)f2bf(v1.y) << 16);
    o.w = (unsigned)f2bf(v1.z) | ((unsigned)f2bf(v1.w) << 16);
    *(uint4*)(xg + (long)p * 1024 + col) = o;
    return;
  }
  __shared__ float tile[64][65];
  const float* in; unsigned short* out;
  int R, C, r0, c0; long base;
  if (id < 1024) {          // W1: [1024][256] -> [256][1024] per expert
    in = W1; out = w1t; R = 1024; C = 256;
    base = (long)(id >> 6) * 262144;
    r0 = ((id >> 2) & 15) * 64; c0 = (id & 3) * 64;
  } else if (id < 2048) {   // W2: [256][1024] -> [1024][256] per expert
    id -= 1024;
    in = W2; out = w2t; R = 256; C = 1024;
    base = (long)(id >> 6) * 262144;
    r0 = ((id >> 4) & 3) * 64; c0 = (id & 15) * 64;
  } else if (id < 2304) {   // Wg1
    id -= 2048;
    in = Wg1; out = wg1t; R = 1024; C = 1024; base = 0;
    r0 = (id >> 4) * 64; c0 = (id & 15) * 64;
  } else {                  // Wg2
    id -= 2304;
    in = Wg2; out = wg2t; R = 1024; C = 1024; base = 0;
    r0 = (id >> 4) * 64; c0 = (id & 15) * 64;
  }
  const int cc = t & 63, rr = t >> 6;
#pragma unroll
  for (int i = 0; i < 16; i++) {
    int r = rr + i * 4;
    tile[r][cc] = in[base + (long)(r0 + r) * C + (c0 + cc)];
  }
  __syncthreads();
#pragma unroll
  for (int i = 0; i < 16; i++) {
    int c = rr + i * 4;
    out[base + (long)(c0 + c) * R + (r0 + cc)] = f2bf(tile[cc][c]);
  }
}

// ---------------- expert 128x128x64 GEMM (m97 structure, compact tile list) ----------------
// A rows are sorted-linear (rowBase + row); C rows sorted (G1) or scattered (G2).
template <bool GELU, bool SCATTER_C>
__global__ __launch_bounds__(256, 4) void gemm_expert(
    const unsigned short* __restrict__ A, const unsigned short* __restrict__ BT,
    const float* __restrict__ bias, unsigned short* __restrict__ Cout,
    int N, int K,
    const int* __restrict__ order, const int* __restrict__ offs,
    const int* __restrict__ tileE, const int* __restrict__ tileR,
    const int* __restrict__ ntl,
    int S, long btStride, int biasStride) {
  const int ti = (int)blockIdx.y;
  if (ti >= ntl[0]) return;
  const int t = (int)threadIdx.x;
  const int lane = t & 63;
  const int w = t >> 6;
  const int wm = w >> 1, wn = w & 1;
  const int tileN = (int)blockIdx.x;

  const int e = tileE[ti];
  const int rowBase = tileR[ti];
  int Me = 4 * offs[e + 1] - rowBase;
  if (Me > 128) Me = 128;
  const unsigned short* bt = BT + (long)e * btStride;
  const float* bs = bias + (long)e * biasStride;

  __shared__ __align__(16) unsigned short lA[128 * 64];
  __shared__ __align__(16) unsigned short lB[128 * 64];

  const unsigned short* aSrc[4];
  const unsigned short* bSrc[4];
  {
    const int q = t & 7;
#pragma unroll
    for (int i = 0; i < 4; i++) {
      const int row = i * 32 + (t >> 3);
      const int koff = ((q * 16) ^ ((row & 7) << 4)) >> 1;
      const int rr = (row < Me) ? row : (Me - 1);
      aSrc[i] = A + (long)(rowBase + rr) * K + koff;
      const int col = tileN * 128 + row;
      bSrc[i] = bt + (long)col * K + koff;
    }
  }

  f32x4 acc[4][4] = {};

  const int KT = K >> 6;
  for (int kt = 0; kt < KT; kt++) {
    __syncthreads();
#pragma unroll
    for (int i = 0; i < 4; i++) {
      gload16(aSrc[i] + (kt << 6), (void*)(lA + i * 2048 + w * 512));
      gload16(bSrc[i] + (kt << 6), (void*)(lB + i * 2048 + w * 512));
    }
    __syncthreads();
#pragma unroll
    for (int kk = 0; kk < 2; kk++) {
      short8 af[4], bfr[4];
      const int kbyte = kk * 64 + (lane >> 4) * 16;
#pragma unroll
      for (int mi = 0; mi < 4; mi++) {
        const int row = wm * 64 + mi * 16 + (lane & 15);
        const int off = row * 128 + (kbyte ^ ((row & 7) << 4));
        af[mi] = *(const short8*)((const char*)lA + off);
      }
#pragma unroll
      for (int ni = 0; ni < 4; ni++) {
        const int row = wn * 64 + ni * 16 + (lane & 15);
        const int off = row * 128 + (kbyte ^ ((row & 7) << 4));
        bfr[ni] = *(const short8*)((const char*)lB + off);
      }
#pragma unroll
      for (int mi = 0; mi < 4; mi++)
#pragma unroll
        for (int ni = 0; ni < 4; ni++)
          acc[mi][ni] = __builtin_amdgcn_mfma_f32_16x16x32_bf16(af[mi], bfr[ni], acc[mi][ni], 0, 0, 0);
    }
  }

  float bcol[4];
#pragma unroll
  for (int ni = 0; ni < 4; ni++)
    bcol[ni] = bs[tileN * 128 + wn * 64 + ni * 16 + (lane & 15)];

#pragma unroll
  for (int mi = 0; mi < 4; mi++) {
#pragma unroll
    for (int j = 0; j < 4; j++) {
      const int lrow = wm * 64 + mi * 16 + ((lane >> 4) * 4) + j;
      if (lrow >= Me) continue;
      const int g = rowBase + lrow;
      long crow;
      if (SCATTER_C) crow = (long)(g & 3) * S + order[g >> 2];   // natural rows
      else crow = g;                                             // sorted rows
#pragma unroll
      for (int ni = 0; ni < 4; ni++) {
        float v = acc[mi][ni][j] + bcol[ni];
        if (GELU) v = gelu_exact(v);
        Cout[crow * (long)N + tileN * 128 + wn * 64 + ni * 16 + (lane & 15)] = f2bf(v);
      }
    }
  }
}

// ---------------- dense 128x128x64 GEMM (m97 structure, 4 blocks/CU, XCD swizzle) ----------------
template <bool GELU, bool OUT_F32>
__global__ __launch_bounds__(256, 4) void gemm_dense128(
    const unsigned short* __restrict__ A, const unsigned short* __restrict__ BT,
    const float* __restrict__ bias, void* __restrict__ Cout,
    int N, int K, int ntiles) {
  const int t = (int)threadIdx.x;
  const int lane = t & 63;
  const int w = t >> 6;
  const int wm = w >> 1, wn = w & 1;

  const int cpx = (int)gridDim.x >> 3;
  const int swz = ((int)blockIdx.x & 7) * cpx + ((int)blockIdx.x >> 3);
  const int mtile = swz / ntiles, ntile = swz % ntiles;

  __shared__ __align__(16) unsigned short lA[128 * 64];
  __shared__ __align__(16) unsigned short lB[128 * 64];

  const unsigned short* aSrc[4];
  const unsigned short* bSrc[4];
  {
    const int q = t & 7;
#pragma unroll
    for (int i = 0; i < 4; i++) {
      const int row = i * 32 + (t >> 3);
      const int koff = ((q * 16) ^ ((row & 7) << 4)) >> 1;
      aSrc[i] = A + (long)(mtile * 128 + row) * K + koff;
      bSrc[i] = BT + (long)(ntile * 128 + row) * K + koff;
    }
  }

  f32x4 acc[4][4] = {};

  const int KT = K >> 6;
  for (int kt = 0; kt < KT; kt++) {
    __syncthreads();
#pragma unroll
    for (int i = 0; i < 4; i++) {
      gload16(aSrc[i] + (kt << 6), (void*)(lA + i * 2048 + w * 512));
      gload16(bSrc[i] + (kt << 6), (void*)(lB + i * 2048 + w * 512));
    }
    __syncthreads();
#pragma unroll
    for (int kk = 0; kk < 2; kk++) {
      short8 af[4], bfr[4];
      const int kbyte = kk * 64 + (lane >> 4) * 16;
#pragma unroll
      for (int mi = 0; mi < 4; mi++) {
        const int row = wm * 64 + mi * 16 + (lane & 15);
        const int off = row * 128 + (kbyte ^ ((row & 7) << 4));
        af[mi] = *(const short8*)((const char*)lA + off);
      }
#pragma unroll
      for (int ni = 0; ni < 4; ni++) {
        const int row = wn * 64 + ni * 16 + (lane & 15);
        const int off = row * 128 + (kbyte ^ ((row & 7) << 4));
        bfr[ni] = *(const short8*)((const char*)lB + off);
      }
#pragma unroll
      for (int mi = 0; mi < 4; mi++)
#pragma unroll
        for (int ni = 0; ni < 4; ni++)
          acc[mi][ni] = __builtin_amdgcn_mfma_f32_16x16x32_bf16(af[mi], bfr[ni], acc[mi][ni], 0, 0, 0);
    }
  }

  float bcol[4];
#pragma unroll
  for (int ni = 0; ni < 4; ni++)
    bcol[ni] = bias[ntile * 128 + wn * 64 + ni * 16 + (lane & 15)];

#pragma unroll
  for (int mi = 0; mi < 4; mi++) {
#pragma unroll
    for (int j = 0; j < 4; j++) {
      const long crow = mtile * 128 + wm * 64 + mi * 16 + ((lane >> 4) * 4) + j;
#pragma unroll
      for (int ni = 0; ni < 4; ni++) {
        float v = acc[mi][ni][j] + bcol[ni];
        if (GELU) v = gelu_exact(v);
        const long cidx = crow * (long)N + ntile * 128 + wn * 64 + ni * 16 + (lane & 15);
        if (OUT_F32) ((float*)Cout)[cidx] = v;
        else ((unsigned short*)Cout)[cidx] = f2bf(v);
      }
    }
  }
}

extern "C" void kernel_launch(void* const* d_in, const int* in_sizes, int n_in,
                              void* d_out, int out_size, void* d_ws, size_t ws_size,
                              hipStream_t stream) {
  const float* x   = (const float*)d_in[0];
  const int*   sid = (const int*)d_in[1];
  const float* W1  = (const float*)d_in[2];
  const float* b1  = (const float*)d_in[3];
  const float* W2  = (const float*)d_in[4];
  const float* b2  = (const float*)d_in[5];
  const float* Wg1 = (const float*)d_in[6];
  const float* bg1 = (const float*)d_in[7];
  const float* Wg2 = (const float*)d_in[8];
  const float* bg2 = (const float*)d_in[9];
  (void)in_sizes; (void)n_in; (void)out_size; (void)ws_size;

  constexpr int D = 1024, H = 256, S = 4096, B = 4;
  constexpr long NT = (long)B * S;  // 16384 token rows

  char* ws = (char*)d_ws;
  unsigned short* xg   = (unsigned short*)(ws);          // sorted x bf16; reused as gbuf
  unsigned short* w1t  = (unsigned short*)(ws + 33554432);
  unsigned short* w2t  = (unsigned short*)(ws + 41943040);
  unsigned short* wg1t = (unsigned short*)(ws + 50331648);
  unsigned short* wg2t = (unsigned short*)(ws + 52428800);
  unsigned short* hbuf = (unsigned short*)(ws + 54525952);
  unsigned short* rout = (unsigned short*)(ws + 62914560);
  int* offs  = (int*)(ws + 96468992);
  int* order = (int*)(ws + 96469248);
  int* tileE = (int*)(ws + 96485632);
  int* tileR = (int*)(ws + 96486208);
  int* ntl   = (int*)(ws + 96486784);

  route_kernel<<<1, 256, 0, stream>>>(sid, S, offs, order, tileE, tileR, ntl);
  prep_kernel<<<dim3(10752), 256, 0, stream>>>(
      x, order, xg, W1, w1t, W2, w2t, Wg1, wg1t, Wg2, wg2t);

  // GEMM1: h = gelu(xg @ W1[e] + b1[e])   [sorted rows in/out]
  gemm_expert<true, false><<<dim3(H / 128, 144), 256, 0, stream>>>(
      xg, w1t, b1, hbuf, H, D, order, offs, tileE, tileR, ntl, S, (long)H * D, H);
  // GEMM2: rout = h @ W2[e] + b2[e]       [sorted in, scatter to natural rows]
  gemm_expert<false, true><<<dim3(D / 128, 144), 256, 0, stream>>>(
      hbuf, w2t, b2, rout, D, H, order, offs, tileE, tileR, ntl, S, (long)D * H, D);
  // GEMM3: g = gelu(rout @ Wg1 + bg1)     [writes xg region (xg no longer needed)]
  gemm_dense128<true, false><<<dim3((unsigned)(NT / 128) * (D / 128)), 256, 0, stream>>>(
      rout, wg1t, bg1, xg, D, D, D / 128);
  // GEMM4: out = g @ Wg2 + bg2            [fp32 to d_out]
  gemm_dense128<false, true><<<dim3((unsigned)(NT / 128) * (D / 128)), 256, 0, stream>>>(
      xg, wg2t, bg2, d_out, D, D, D / 128);
}